// Round 16
// baseline (1053.441 us; speedup 1.0000x reference)
//
#include <hip/hip_runtime.h>

// ---------------------------------------------------------------------------
// MutualRec forward: 5x GATv2 + ChebConv(k=3) + mutualistic MLP + edge dots
// R16: pass consolidation on R15 (MFMA GEMMs + 32-lane edge kernels):
//   - dual-grouping rate CSR build (1 hist + 1 scatter for both orderings)
//   - 2-output MFMA projection kernel (shared X stream)
//   - paired dot kernel (pos+neg in one launch)
// ---------------------------------------------------------------------------

#define LRELU_SLOPE 0.2f
#define MFMA_BLOCKS 1024
#define EDGE_BLOCKS 2048

typedef unsigned short u16;
typedef unsigned int uint32;
typedef __attribute__((ext_vector_type(8))) short short8;
typedef __attribute__((ext_vector_type(4))) float f32x4;

__device__ __forceinline__ float b2f(u16 u) {
  return __uint_as_float(((uint32)u) << 16);
}
__device__ __forceinline__ u16 f2b(float f) {
  uint32 u = __float_as_uint(f);
  uint32 r = (u + 0x7fffu + ((u >> 16) & 1u)) >> 16;
  return (u16)r;
}
__device__ __forceinline__ float blo(uint32 p) { return __uint_as_float(p << 16); }
__device__ __forceinline__ float bhi(uint32 p) { return __uint_as_float(p & 0xffff0000u); }
__device__ __forceinline__ uint32 packb(float lo, float hi) {
  return (uint32)f2b(lo) | ((uint32)f2b(hi) << 16);
}

// ---- f32 -> bf16 table conversion (vectorized) ----
__global__ void cvt_k(const float4* __restrict__ X, ushort4* __restrict__ Y, int n4) {
  const int stride = gridDim.x * blockDim.x;
  for (int i = blockIdx.x * blockDim.x + threadIdx.x; i < n4; i += stride) {
    const float4 v = X[i];
    ushort4 o;
    o.x = f2b(v.x); o.y = f2b(v.y); o.z = f2b(v.z); o.w = f2b(v.w);
    Y[i] = o;
  }
}

// ---- W[nmat][64][64] f32 -> lane-ordered bf16 B-fragments ----
__global__ void wfrag_k(const float* __restrict__ W, u16* __restrict__ fb, int nmat) {
  const int total = nmat * 4096;
  const int stride = gridDim.x * blockDim.x;
  for (int i = blockIdx.x * blockDim.x + threadIdx.x; i < total; i += stride) {
    const int mat = i >> 12, rem = i & 4095;
    const int l = rem >> 6, r = rem & 63;
    const int kc = r >> 5, cb = (r >> 3) & 3, j = r & 7;
    const int k = kc * 32 + ((l >> 4) & 3) * 8 + j;
    const int col = cb * 16 + (l & 15);
    fb[i] = f2b(W[(size_t)mat * 4096 + k * 64 + col]);
  }
}

// ---- MFMA GEMM: Y[N,64] = sum_i X_i[N,64] @ W_i + b  (bf16 I/O, f32 acc) ----
template <int NIN>
__global__ void mfma_g_k(const u16* __restrict__ X0, const u16* __restrict__ X1,
                         const u16* __restrict__ X2,
                         const u16* __restrict__ F0, const u16* __restrict__ F1,
                         const u16* __restrict__ F2,
                         const float* __restrict__ b, u16* __restrict__ Y, int N) {
  const int lane = threadIdx.x & 63;
  const int gw = (blockIdx.x * blockDim.x + threadIdx.x) >> 6;
  const int nw = (gridDim.x * blockDim.x) >> 6;
  const int lo = lane & 15, hi = lane >> 4;
  short8 bf[NIN][2][4];
#pragma unroll
  for (int i = 0; i < NIN; ++i) {
    const u16* Fi = (i == 0) ? F0 : ((i == 1) ? F1 : F2);
#pragma unroll
    for (int kc = 0; kc < 2; ++kc)
#pragma unroll
      for (int cb = 0; cb < 4; ++cb)
        bf[i][kc][cb] = *(const short8*)(Fi + (size_t)lane * 64 + kc * 32 + cb * 8);
  }
  float bcol[4];
#pragma unroll
  for (int cb = 0; cb < 4; ++cb) bcol[cb] = b[cb * 16 + lo];
  const int ntile = (N + 15) >> 4;
  for (int t = gw; t < ntile; t += nw) {
    int arow = t * 16 + lo;
    if (arow >= N) arow = N - 1;
    f32x4 acc[4];
#pragma unroll
    for (int cb = 0; cb < 4; ++cb) {
      acc[cb][0] = bcol[cb]; acc[cb][1] = bcol[cb];
      acc[cb][2] = bcol[cb]; acc[cb][3] = bcol[cb];
    }
#pragma unroll
    for (int i = 0; i < NIN; ++i) {
      const u16* Xi = (i == 0) ? X0 : ((i == 1) ? X1 : X2);
      const short8 a0 = *(const short8*)(Xi + (size_t)arow * 64 + hi * 8);
      const short8 a1 = *(const short8*)(Xi + (size_t)arow * 64 + 32 + hi * 8);
#pragma unroll
      for (int cb = 0; cb < 4; ++cb)
        acc[cb] = __builtin_amdgcn_mfma_f32_16x16x32_bf16(a0, bf[i][0][cb], acc[cb], 0, 0, 0);
#pragma unroll
      for (int cb = 0; cb < 4; ++cb)
        acc[cb] = __builtin_amdgcn_mfma_f32_16x16x32_bf16(a1, bf[i][1][cb], acc[cb], 0, 0, 0);
    }
#pragma unroll
    for (int cb = 0; cb < 4; ++cb) {
#pragma unroll
      for (int j = 0; j < 4; ++j) {
        const int row = t * 16 + hi * 4 + j;
        if (row < N) Y[(size_t)row * 64 + cb * 16 + lo] = f2b(acc[cb][j]);
      }
    }
  }
}

// ---- 2-output MFMA: Y0 = X@W0+b0, Y1 = X@W1+b1 (one X stream) ----
__global__ void mfma_g2_k(const u16* __restrict__ X,
                          const u16* __restrict__ F0, const u16* __restrict__ F1,
                          const float* __restrict__ b0, const float* __restrict__ b1,
                          u16* __restrict__ Y0, u16* __restrict__ Y1, int N) {
  const int lane = threadIdx.x & 63;
  const int gw = (blockIdx.x * blockDim.x + threadIdx.x) >> 6;
  const int nw = (gridDim.x * blockDim.x) >> 6;
  const int lo = lane & 15, hi = lane >> 4;
  short8 bfA[2][4], bfB[2][4];
#pragma unroll
  for (int kc = 0; kc < 2; ++kc)
#pragma unroll
    for (int cb = 0; cb < 4; ++cb) {
      bfA[kc][cb] = *(const short8*)(F0 + (size_t)lane * 64 + kc * 32 + cb * 8);
      bfB[kc][cb] = *(const short8*)(F1 + (size_t)lane * 64 + kc * 32 + cb * 8);
    }
  float bc0[4], bc1[4];
#pragma unroll
  for (int cb = 0; cb < 4; ++cb) { bc0[cb] = b0[cb * 16 + lo]; bc1[cb] = b1[cb * 16 + lo]; }
  const int ntile = (N + 15) >> 4;
  for (int t = gw; t < ntile; t += nw) {
    int arow = t * 16 + lo;
    if (arow >= N) arow = N - 1;
    const short8 a0 = *(const short8*)(X + (size_t)arow * 64 + hi * 8);
    const short8 a1 = *(const short8*)(X + (size_t)arow * 64 + 32 + hi * 8);
    f32x4 accA[4], accB[4];
#pragma unroll
    for (int cb = 0; cb < 4; ++cb) {
      accA[cb][0] = bc0[cb]; accA[cb][1] = bc0[cb]; accA[cb][2] = bc0[cb]; accA[cb][3] = bc0[cb];
      accB[cb][0] = bc1[cb]; accB[cb][1] = bc1[cb]; accB[cb][2] = bc1[cb]; accB[cb][3] = bc1[cb];
    }
#pragma unroll
    for (int cb = 0; cb < 4; ++cb) {
      accA[cb] = __builtin_amdgcn_mfma_f32_16x16x32_bf16(a0, bfA[0][cb], accA[cb], 0, 0, 0);
      accA[cb] = __builtin_amdgcn_mfma_f32_16x16x32_bf16(a1, bfA[1][cb], accA[cb], 0, 0, 0);
      accB[cb] = __builtin_amdgcn_mfma_f32_16x16x32_bf16(a0, bfB[0][cb], accB[cb], 0, 0, 0);
      accB[cb] = __builtin_amdgcn_mfma_f32_16x16x32_bf16(a1, bfB[1][cb], accB[cb], 0, 0, 0);
    }
#pragma unroll
    for (int cb = 0; cb < 4; ++cb) {
#pragma unroll
      for (int j = 0; j < 4; ++j) {
        const int row = t * 16 + hi * 4 + j;
        if (row < N) {
          Y0[(size_t)row * 64 + cb * 16 + lo] = f2b(accA[cb][j]);
          Y1[(size_t)row * 64 + cb * 16 + lo] = f2b(accB[cb][j]);
        }
      }
    }
  }
}

// ========================= CSR build (counting sort) =======================
__global__ void hist_k(const int* __restrict__ key, int* __restrict__ cnt, int E) {
  const int e = blockIdx.x * blockDim.x + threadIdx.x;
  if (e < E) atomicAdd(cnt + key[e], 1);
}
// dual histogram: cntS[src]++ and cntD[dst]++ in one pass
__global__ void hist2_k(const int* __restrict__ src, const int* __restrict__ dst,
                        int* __restrict__ cntS, int* __restrict__ cntD, int E) {
  const int e = blockIdx.x * blockDim.x + threadIdx.x;
  if (e < E) {
    atomicAdd(cntS + src[e], 1);
    atomicAdd(cntD + dst[e], 1);
  }
}

__global__ void scan1_k(const int* __restrict__ in, int* __restrict__ out,
                        int* __restrict__ bsum, int n) {
  __shared__ int tmp[256];
  const int t = threadIdx.x;
  const int base = blockIdx.x * 1024 + t * 4;
  int v0 = (base + 0 < n) ? in[base + 0] : 0;
  int v1 = (base + 1 < n) ? in[base + 1] : 0;
  int v2 = (base + 2 < n) ? in[base + 2] : 0;
  int v3 = (base + 3 < n) ? in[base + 3] : 0;
  const int s = v0 + v1 + v2 + v3;
  tmp[t] = s;
  __syncthreads();
  for (int off = 1; off < 256; off <<= 1) {
    const int x = (t >= off) ? tmp[t - off] : 0;
    __syncthreads();
    tmp[t] += x;
    __syncthreads();
  }
  const int excl = tmp[t] - s;
  if (t == 255) bsum[blockIdx.x] = tmp[255];
  if (base + 0 < n) out[base + 0] = excl;
  if (base + 1 < n) out[base + 1] = excl + v0;
  if (base + 2 < n) out[base + 2] = excl + v0 + v1;
  if (base + 3 < n) out[base + 3] = excl + v0 + v1 + v2;
}
__global__ void scan2_k(int* __restrict__ bsum, int nb) {
  if (threadIdx.x == 0) {
    int acc = 0;
    for (int i = 0; i < nb; ++i) { const int v = bsum[i]; bsum[i] = acc; acc += v; }
  }
}
__global__ void scan3_k(int* __restrict__ out, const int* __restrict__ bsum, int n) {
  const int i = blockIdx.x * blockDim.x + threadIdx.x;
  if (i < n) out[i] += bsum[i >> 10];
}

__global__ void scatter_k(const int* __restrict__ key, const int* __restrict__ other,
                          int* __restrict__ cursor, int* __restrict__ srt, int E) {
  const int e = blockIdx.x * blockDim.x + threadIdx.x;
  if (e < E) {
    const int p = atomicAdd(cursor + key[e], 1);
    srt[p] = other[e];
  }
}
// dual scatter: srtD (src grouped by dst) and srtS (dst grouped by src)
__global__ void scatter2_k(const int* __restrict__ src, const int* __restrict__ dst,
                           int* __restrict__ curS, int* __restrict__ curD,
                           int* __restrict__ srtS, int* __restrict__ srtD, int E) {
  const int e = blockIdx.x * blockDim.x + threadIdx.x;
  if (e < E) {
    const int s = src[e], d = dst[e];
    const int p = atomicAdd(curD + d, 1);
    srtD[p] = s;
    const int q = atomicAdd(curS + s, 1);
    srtS[q] = d;
  }
}

// =================== 32-lane-subwave edge kernels (bf16) ===================
__global__ void gat32_k(const u16* __restrict__ fs, const u16* __restrict__ fd,
                        const float* __restrict__ attn,
                        const int* __restrict__ rowptr, const int* __restrict__ nbr,
                        u16* __restrict__ out, int N) {
  const int lane = threadIdx.x & 63;
  const int l = lane & 31, half = lane >> 5;
  const int wid = (blockIdx.x * blockDim.x + threadIdx.x) >> 6;
  const int nw = (gridDim.x * blockDim.x) >> 6;
  const float awlo = attn[2 * l], awhi = attn[2 * l + 1];
  const uint32* fs32 = (const uint32*)fs;
  const uint32* fd32 = (const uint32*)fd;
  uint32* out32 = (uint32*)out;
  for (int n0 = wid * 2; n0 < N; n0 += nw * 2) {
    const int n = n0 + half;
    const bool act = n < N;
    const int beg = act ? rowptr[n] : 0;
    const int end = act ? rowptr[n + 1] : 0;
    float fdlo = 0.0f, fdhi = 0.0f;
    if (act) {
      const uint32 fp = fd32[(size_t)n * 32 + l];
      fdlo = blo(fp); fdhi = bhi(fp);
    }
    float aclo = 0.0f, achi = 0.0f, den = 0.0f;
    int e = beg;
    for (; e + 1 < end; e += 2) {
      const int s0 = nbr[e], s1 = nbr[e + 1];
      const uint32 f0 = fs32[(size_t)s0 * 32 + l];
      const uint32 f1 = fs32[(size_t)s1 * 32 + l];
      const float f0l = blo(f0), f0h = bhi(f0);
      const float f1l = blo(f1), f1h = bhi(f1);
      float v0l = f0l + fdlo; v0l = v0l > 0.0f ? v0l : LRELU_SLOPE * v0l;
      float v0h = f0h + fdhi; v0h = v0h > 0.0f ? v0h : LRELU_SLOPE * v0h;
      float v1l = f1l + fdlo; v1l = v1l > 0.0f ? v1l : LRELU_SLOPE * v1l;
      float v1h = f1h + fdhi; v1h = v1h > 0.0f ? v1h : LRELU_SLOPE * v1h;
      float p0 = fmaf(v0l, awlo, v0h * awhi);
      float p1 = fmaf(v1l, awlo, v1h * awhi);
#pragma unroll
      for (int o = 16; o; o >>= 1) {
        p0 += __shfl_xor(p0, o, 64);
        p1 += __shfl_xor(p1, o, 64);
      }
      const float e0 = __expf(p0), e1 = __expf(p1);
      den += e0 + e1;
      aclo = fmaf(e0, f0l, aclo); achi = fmaf(e0, f0h, achi);
      aclo = fmaf(e1, f1l, aclo); achi = fmaf(e1, f1h, achi);
    }
    if (e < end) {
      const int s0 = nbr[e];
      const uint32 f0 = fs32[(size_t)s0 * 32 + l];
      const float f0l = blo(f0), f0h = bhi(f0);
      float v0l = f0l + fdlo; v0l = v0l > 0.0f ? v0l : LRELU_SLOPE * v0l;
      float v0h = f0h + fdhi; v0h = v0h > 0.0f ? v0h : LRELU_SLOPE * v0h;
      float p0 = fmaf(v0l, awlo, v0h * awhi);
#pragma unroll
      for (int o = 16; o; o >>= 1) p0 += __shfl_xor(p0, o, 64);
      const float e0 = __expf(p0);
      den += e0;
      aclo = fmaf(e0, f0l, aclo); achi = fmaf(e0, f0h, achi);
    }
    const float inv = den > 0.0f ? 1.0f / den : 0.0f;
    if (act) out32[(size_t)n * 32 + l] = packb(aclo * inv, achi * inv);
  }
}

template <int MODE>
__global__ void cheb32_k(const u16* __restrict__ x, const u16* __restrict__ T0,
                         const u16* __restrict__ Tp, const float* __restrict__ dinv,
                         const float* __restrict__ lam,
                         const int* __restrict__ rowptr, const int* __restrict__ nbr,
                         u16* __restrict__ outT, int N) {
  const float re = 2.0f / lam[0];
  const int lane = threadIdx.x & 63;
  const int l = lane & 31, half = lane >> 5;
  const int wid = (blockIdx.x * blockDim.x + threadIdx.x) >> 6;
  const int nw = (gridDim.x * blockDim.x) >> 6;
  const uint32* x32 = (const uint32*)x;
  const uint32* T032 = (const uint32*)T0;
  const uint32* Tp32 = (const uint32*)Tp;
  uint32* o32 = (uint32*)outT;
  for (int n0 = wid * 2; n0 < N; n0 += nw * 2) {
    const int n = n0 + half;
    const bool act = n < N;
    const int beg = act ? rowptr[n] : 0;
    const int end = act ? rowptr[n + 1] : 0;
    float aclo = 0.0f, achi = 0.0f;
    int e = beg;
    for (; e + 1 < end; e += 2) {
      const int s0 = nbr[e], s1 = nbr[e + 1];
      const uint32 f0 = x32[(size_t)s0 * 32 + l];
      const uint32 f1 = x32[(size_t)s1 * 32 + l];
      const float d0 = dinv[s0], d1 = dinv[s1];
      aclo = fmaf(blo(f0), d0, aclo); achi = fmaf(bhi(f0), d0, achi);
      aclo = fmaf(blo(f1), d1, aclo); achi = fmaf(bhi(f1), d1, achi);
    }
    if (e < end) {
      const int s0 = nbr[e];
      const uint32 f0 = x32[(size_t)s0 * 32 + l];
      const float d0 = dinv[s0];
      aclo = fmaf(blo(f0), d0, aclo); achi = fmaf(bhi(f0), d0, achi);
    }
    if (!act) continue;
    const float dn = dinv[n];
    const float hl = aclo * dn, hh = achi * dn;
    float rl, rh;
    if (MODE == 1) {
      const uint32 t0 = T032[(size_t)n * 32 + l];
      rl = -re * hl + (re - 1.0f) * blo(t0);
      rh = -re * hh + (re - 1.0f) * bhi(t0);
    } else {
      const uint32 t0 = T032[(size_t)n * 32 + l];
      const uint32 tp = Tp32[(size_t)n * 32 + l];
      rl = -2.0f * re * hl + 2.0f * (re - 1.0f) * blo(tp) - blo(t0);
      rh = -2.0f * re * hh + 2.0f * (re - 1.0f) * bhi(tp) - bhi(t0);
    }
    o32[(size_t)n * 32 + l] = packb(rl, rh);
  }
}

__global__ void dinv_k(const int* __restrict__ rowptr, float* __restrict__ dinv, int N) {
  const int i = blockIdx.x * blockDim.x + threadIdx.x;
  if (i < N) {
    const float deg = (float)(rowptr[i + 1] - rowptr[i]);
    dinv[i] = rsqrtf(fmaxf(deg, 1.0f));
  }
}

// ---- mutualistic (bf16 I/O) ----
__global__ void mut_k(const u16* __restrict__ hP, const u16* __restrict__ hS,
                      u16* __restrict__ mP, u16* __restrict__ mS, int N) {
  const int lane = threadIdx.x & 63;
  const int u = (blockIdx.x * blockDim.x + threadIdx.x) >> 6;
  if (u >= N) return;
  const float p = b2f(hP[(size_t)u * 64 + lane]);
  const float s = b2f(hS[(size_t)u * 64 + lane]);
  const float m = p * s;
  float mxp = p, mxs = s;
#pragma unroll
  for (int o = 32; o; o >>= 1) {
    mxp = fmaxf(mxp, __shfl_xor(mxp, o, 64));
    mxs = fmaxf(mxs, __shfl_xor(mxs, o, 64));
  }
  const float ep = __expf(p - mxp);
  const float es = __expf(s - mxs);
  float sp = ep, ss = es;
#pragma unroll
  for (int o = 32; o; o >>= 1) {
    sp += __shfl_xor(sp, o, 64);
    ss += __shfl_xor(ss, o, 64);
  }
  mP[(size_t)u * 64 + lane] = f2b(m * (ep / sp));
  mS[(size_t)u * 64 + lane] = f2b(m * (es / ss));
}

// ---- paired edge dot: two edge lists over the same tables ----
__global__ void dot2_k(const u16* __restrict__ A, const u16* __restrict__ Bm,
                       const int* __restrict__ src1, const int* __restrict__ dst1,
                       float* __restrict__ out1, int E1,
                       const int* __restrict__ src2, const int* __restrict__ dst2,
                       float* __restrict__ out2, int E2) {
  const int lane = threadIdx.x & 63;
  const int l = lane & 31, half = lane >> 5;
  const int wid = (blockIdx.x * blockDim.x + threadIdx.x) >> 6;
  const int nw = (gridDim.x * blockDim.x) >> 6;
  const uint32* A32 = (const uint32*)A;
  const uint32* B32 = (const uint32*)Bm;
  const int total = E1 + E2;
  for (int g0 = wid * 4; g0 < total; g0 += nw * 4) {
    const int gA = g0 + half;
    const int gB = g0 + 2 + half;
    const int gAc = gA < total ? gA : total - 1;
    const int gBc = gB < total ? gB : total - 1;
    const bool a1st = gAc < E1, b1st = gBc < E1;
    const int sA = a1st ? src1[gAc] : src2[gAc - E1];
    const int dA = a1st ? dst1[gAc] : dst2[gAc - E1];
    const int sB = b1st ? src1[gBc] : src2[gBc - E1];
    const int dB = b1st ? dst1[gBc] : dst2[gBc - E1];
    const uint32 a0 = A32[(size_t)sA * 32 + l];
    const uint32 b0 = B32[(size_t)dA * 32 + l];
    const uint32 a1 = A32[(size_t)sB * 32 + l];
    const uint32 b1 = B32[(size_t)dB * 32 + l];
    float p0 = fmaf(blo(a0), blo(b0), bhi(a0) * bhi(b0));
    float p1 = fmaf(blo(a1), blo(b1), bhi(a1) * bhi(b1));
#pragma unroll
    for (int o = 16; o; o >>= 1) {
      p0 += __shfl_xor(p0, o, 64);
      p1 += __shfl_xor(p1, o, 64);
    }
    if (l == 0) {
      if (gA < total) {
        if (a1st) out1[gA] = p0; else out2[gA - E1] = p0;
      }
      if (gB < total) {
        if (b1st) out1[gB] = p1; else out2[gB - E1] = p1;
      }
    }
  }
}

// ---------------------------------------------------------------------------

extern "C" void kernel_launch(void* const* d_in, const int* in_sizes, int n_in,
                              void* d_out, int out_size, void* d_ws, size_t ws_size,
                              hipStream_t stream) {
  const float* user_emb = (const float*)d_in[0];
  const float* item_emb = (const float*)d_in[1];
  const int* rate_src = (const int*)d_in[2];
  const int* rate_dst = (const int*)d_in[3];
  const int* link_src = (const int*)d_in[4];
  const int* link_dst = (const int*)d_in[5];
  const int* neg_rate_src = (const int*)d_in[6];
  const int* neg_rate_dst = (const int*)d_in[7];
  const int* neg_link_src = (const int*)d_in[8];
  const int* neg_link_dst = (const int*)d_in[9];
  const float* lam = (const float*)d_in[10];
  const float* gat_Wsrc = (const float*)d_in[11];
  const float* gat_bsrc = (const float*)d_in[12];
  const float* gat_Wdst = (const float*)d_in[13];
  const float* gat_bdst = (const float*)d_in[14];
  const float* gat_attn = (const float*)d_in[15];
  const float* W_out = (const float*)d_in[16];
  const float* b_out = (const float*)d_in[17];
  const float* cheb_W = (const float*)d_in[18];
  const float* cheb_b = (const float*)d_in[19];
  const float* Wc = (const float*)d_in[20];
  const float* bc = (const float*)d_in[21];
  const float* Wsm = (const float*)d_in[22];
  const float* bs = (const float*)d_in[23];
  const float* WpP = (const float*)d_in[24];
  const float* bpP = (const float*)d_in[25];
  const float* WpS = (const float*)d_in[26];
  const float* bpS = (const float*)d_in[27];

  const int NU = in_sizes[0] / 64;
  const int NI = in_sizes[1] / 64;
  const int NR = in_sizes[2];
  const int NL = in_sizes[4];
  const int NMAX = NU > NI ? NU : NI;
  const size_t MAT = (size_t)NMAX * 64;
  const int FR = 4096;

  u16* ub = (u16*)d_ws;
  u16* ib = ub + (size_t)NU * 64;
  u16* B0 = ib + (size_t)NI * 64;
  u16* B1 = B0 + MAT;
  u16* B2 = B1 + MAT;
  u16* B3 = B2 + MAT;
  u16* B4 = B3 + MAT;
  u16* B5 = B4 + MAT;
  u16* B6 = B5 + MAT;
  u16* B7 = B6 + MAT;
  u16* fb = B7 + MAT;
  u16* fbWsrc = fb;
  u16* fbWdst = fb + 5 * FR;
  u16* fbWout = fb + 10 * FR;
  u16* fbCheb = fb + 12 * FR;
  u16* fbWc = fb + 15 * FR;
  u16* fbWsm = fb + 17 * FR;
  u16* fbWpP = fb + 19 * FR;
  u16* fbWpS = fb + 21 * FR;
  int* ip = (int*)(fb + 23 * FR);
  int* rp_rd = ip;                     // NI+1
  int* rp_rs = rp_rd + (NI + 1);       // NU+1
  int* rp_ld = rp_rs + (NU + 1);       // NU+1
  int* srt_rd = rp_ld + (NU + 1);      // NR
  int* srt_rs = srt_rd + NR;           // NR
  int* srt_ld = srt_rs + NR;           // NL
  int* cursorA = srt_ld + NL;          // NMAX+1
  int* cursorB = cursorA + (NMAX + 1); // NMAX+1
  int* bsum = cursorB + (NMAX + 1);    // 256
  float* dinv = (float*)(bsum + 256);  // NU

  const int B64 = 64;

  // ---- bf16 copies + W fragment prep ----
  cvt_k<<<1024, 256, 0, stream>>>((const float4*)user_emb, (ushort4*)ub, NU * 16);
  cvt_k<<<1024, 256, 0, stream>>>((const float4*)item_emb, (ushort4*)ib, NI * 16);
  wfrag_k<<<20, 256, 0, stream>>>(gat_Wsrc, fbWsrc, 5);
  wfrag_k<<<20, 256, 0, stream>>>(gat_Wdst, fbWdst, 5);
  wfrag_k<<<8, 256, 0, stream>>>(W_out, fbWout, 2);
  wfrag_k<<<12, 256, 0, stream>>>(cheb_W, fbCheb, 3);
  wfrag_k<<<8, 256, 0, stream>>>(Wc, fbWc, 2);
  wfrag_k<<<8, 256, 0, stream>>>(Wsm, fbWsm, 2);
  wfrag_k<<<8, 256, 0, stream>>>(WpP, fbWpP, 2);
  wfrag_k<<<8, 256, 0, stream>>>(WpS, fbWpS, 2);

  // ---- rate CSR (both orderings, one pass) ----
  hipMemsetAsync(cursorA, 0, (size_t)(NU + 1) * 4, stream);
  hipMemsetAsync(cursorB, 0, (size_t)(NI + 1) * 4, stream);
  hist2_k<<<(NR + 255) / 256, 256, 0, stream>>>(rate_src, rate_dst, cursorA, cursorB, NR);
  {
    const int n1 = NU + 1, nb = (n1 + 1023) / 1024;
    scan1_k<<<nb, 256, 0, stream>>>(cursorA, rp_rs, bsum, n1);
    scan2_k<<<1, 64, 0, stream>>>(bsum, nb);
    scan3_k<<<(n1 + 255) / 256, 256, 0, stream>>>(rp_rs, bsum, n1);
  }
  {
    const int n1 = NI + 1, nb = (n1 + 1023) / 1024;
    scan1_k<<<nb, 256, 0, stream>>>(cursorB, rp_rd, bsum, n1);
    scan2_k<<<1, 64, 0, stream>>>(bsum, nb);
    scan3_k<<<(n1 + 255) / 256, 256, 0, stream>>>(rp_rd, bsum, n1);
  }
  hipMemcpyAsync(cursorA, rp_rs, (size_t)NU * 4, hipMemcpyDeviceToDevice, stream);
  hipMemcpyAsync(cursorB, rp_rd, (size_t)NI * 4, hipMemcpyDeviceToDevice, stream);
  scatter2_k<<<(NR + 255) / 256, 256, 0, stream>>>(rate_src, rate_dst, cursorA, cursorB,
                                                   srt_rs, srt_rd, NR);
  // ---- link CSR (by dst) ----
  hipMemsetAsync(cursorA, 0, (size_t)(NU + 1) * 4, stream);
  hist_k<<<(NL + 255) / 256, 256, 0, stream>>>(link_dst, cursorA, NL);
  {
    const int n1 = NU + 1, nb = (n1 + 1023) / 1024;
    scan1_k<<<nb, 256, 0, stream>>>(cursorA, rp_ld, bsum, n1);
    scan2_k<<<1, 64, 0, stream>>>(bsum, nb);
    scan3_k<<<(n1 + 255) / 256, 256, 0, stream>>>(rp_ld, bsum, n1);
  }
  hipMemcpyAsync(cursorA, rp_ld, (size_t)NU * 4, hipMemcpyDeviceToDevice, stream);
  scatter_k<<<(NL + 255) / 256, 256, 0, stream>>>(link_dst, link_src, cursorA, srt_ld, NL);

  // ---- projections (2-output MFMA): fs0->B0, fd1->B1 ; fd2->B2, fd3->B3 ----
  mfma_g2_k<<<MFMA_BLOCKS, 256, 0, stream>>>(ub, fbWsrc + 0 * FR, fbWdst + 1 * FR,
      gat_bsrc + 0 * B64, gat_bdst + 1 * B64, B0, B1, NU);
  mfma_g2_k<<<MFMA_BLOCKS, 256, 0, stream>>>(ub, fbWdst + 2 * FR, fbWdst + 3 * FR,
      gat_bdst + 2 * B64, gat_bdst + 3 * B64, B2, B3, NU);
  // ---- item projections: fd0->B4, fs1->B5 ----
  mfma_g2_k<<<MFMA_BLOCKS, 256, 0, stream>>>(ib, fbWdst + 0 * FR, fbWsrc + 1 * FR,
      gat_bdst + 0 * B64, gat_bsrc + 1 * B64, B4, B5, NI);

  // ---- gat0 -> B6 (h1_item) ; gat1 -> B7 (h2_user) ----
  gat32_k<<<EDGE_BLOCKS, 256, 0, stream>>>(B0, B4, gat_attn + 0 * B64, rp_rd, srt_rd, B6, NI);
  gat32_k<<<EDGE_BLOCKS, 256, 0, stream>>>(B5, B1, gat_attn + 1 * B64, rp_rs, srt_rs, B7, NU);

  // ---- fs2 = h1_item @ Ws2 -> B0 ; gat2 -> B4 (item_infl) ----
  mfma_g_k<1><<<MFMA_BLOCKS, 256, 0, stream>>>(B6, nullptr, nullptr,
      fbWsrc + 2 * FR, nullptr, nullptr, gat_bsrc + 2 * B64, B0, NI);
  gat32_k<<<EDGE_BLOCKS, 256, 0, stream>>>(B0, B2, gat_attn + 2 * B64, rp_rs, srt_rs, B4, NU);

  // ---- fs3 = h2_user @ Ws3 -> B5 ; gat3 -> B2 (social_item) ----
  mfma_g_k<1><<<MFMA_BLOCKS, 256, 0, stream>>>(B7, nullptr, nullptr,
      fbWsrc + 3 * FR, nullptr, nullptr, gat_bsrc + 3 * B64, B5, NU);
  gat32_k<<<EDGE_BLOCKS, 256, 0, stream>>>(B5, B3, gat_attn + 3 * B64, rp_ld, srt_ld, B2, NU);

  // ---- user_pref = [item_infl(B4), social_item(B2)] @ W_out -> B0 ----
  mfma_g_k<2><<<MFMA_BLOCKS, 256, 0, stream>>>(B4, B2, nullptr,
      fbWout + 0 * FR, fbWout + 1 * FR, nullptr, b_out, B0, NU);

  // ---- ChebConv(k=3): T1->B5, T2->B3, rst->B6 ----
  dinv_k<<<(NU + 255) / 256, 256, 0, stream>>>(rp_ld, dinv, NU);
  cheb32_k<1><<<EDGE_BLOCKS, 256, 0, stream>>>(ub, ub, nullptr, dinv, lam,
                                               rp_ld, srt_ld, B5, NU);
  cheb32_k<2><<<EDGE_BLOCKS, 256, 0, stream>>>(B5, ub, B5, dinv, lam,
                                               rp_ld, srt_ld, B3, NU);
  mfma_g_k<3><<<MFMA_BLOCKS, 256, 0, stream>>>(ub, B5, B3,
      fbCheb + 0 * FR, fbCheb + 1 * FR, fbCheb + 2 * FR, cheb_b, B6, NU);

  // ---- rst projections: fs4->B4, fd4->B2 ; gat4 -> B5 (user_social) ----
  mfma_g2_k<<<MFMA_BLOCKS, 256, 0, stream>>>(B6, fbWsrc + 4 * FR, fbWdst + 4 * FR,
      gat_bsrc + 4 * B64, gat_bdst + 4 * B64, B4, B2, NU);
  gat32_k<<<EDGE_BLOCKS, 256, 0, stream>>>(B4, B2, gat_attn + 4 * B64, rp_ld, srt_ld, B5, NU);

  // ---- mutualistic: h_uP->B4, h_uS->B2 ----
  mfma_g_k<2><<<MFMA_BLOCKS, 256, 0, stream>>>(B0, ub, nullptr,
      fbWc + 0 * FR, fbWc + 1 * FR, nullptr, bc, B4, NU);
  mfma_g_k<2><<<MFMA_BLOCKS, 256, 0, stream>>>(B5, ub, nullptr,
      fbWsm + 0 * FR, fbWsm + 1 * FR, nullptr, bs, B2, NU);
  mut_k<<<(NU + 3) / 4, 256, 0, stream>>>(B4, B2, B3, B7, NU);  // mP->B3, mS->B7
  mfma_g_k<2><<<MFMA_BLOCKS, 256, 0, stream>>>(B3, B4, nullptr,
      fbWpP + 0 * FR, fbWpP + 1 * FR, nullptr, bpP, B0, NU);
  mfma_g_k<2><<<MFMA_BLOCKS, 256, 0, stream>>>(B7, B2, nullptr,
      fbWpS + 0 * FR, fbWpS + 1 * FR, nullptr, bpS, B5, NU);

  // ---- predictors (paired) ----
  float* out = (float*)d_out;
  dot2_k<<<EDGE_BLOCKS, 256, 0, stream>>>(B0, ib, rate_src, rate_dst, out, NR,
                                          neg_rate_src, neg_rate_dst, out + NR, NR);
  dot2_k<<<EDGE_BLOCKS, 256, 0, stream>>>(B5, ub, link_src, link_dst, out + 2 * (size_t)NR, NL,
                                          neg_link_src, neg_link_dst, out + 2 * (size_t)NR + NL, NL);
}

// Round 17
// 1016.911 us; speedup vs baseline: 1.0359x; 1.0359x over previous
//
#include <hip/hip_runtime.h>

// ---------------------------------------------------------------------------
// MutualRec forward: 5x GATv2 + ChebConv(k=3) + mutualistic MLP + edge dots
// R17: R15 structure (separate CSR builds, separate dot launches) +
//   mfma_g2_k 2-output projections (the one R16 change with clean mechanism).
//   Lesson from R16: never fuse two independent random-atomic passes into
//   one thread (dependent RMW latency chains serialize).
// ---------------------------------------------------------------------------

#define LRELU_SLOPE 0.2f
#define MFMA_BLOCKS 1024
#define EDGE_BLOCKS 2048

typedef unsigned short u16;
typedef unsigned int uint32;
typedef __attribute__((ext_vector_type(8))) short short8;
typedef __attribute__((ext_vector_type(4))) float f32x4;

__device__ __forceinline__ float b2f(u16 u) {
  return __uint_as_float(((uint32)u) << 16);
}
__device__ __forceinline__ u16 f2b(float f) {
  uint32 u = __float_as_uint(f);
  uint32 r = (u + 0x7fffu + ((u >> 16) & 1u)) >> 16;
  return (u16)r;
}
__device__ __forceinline__ float blo(uint32 p) { return __uint_as_float(p << 16); }
__device__ __forceinline__ float bhi(uint32 p) { return __uint_as_float(p & 0xffff0000u); }
__device__ __forceinline__ uint32 packb(float lo, float hi) {
  return (uint32)f2b(lo) | ((uint32)f2b(hi) << 16);
}

// ---- f32 -> bf16 table conversion (vectorized) ----
__global__ void cvt_k(const float4* __restrict__ X, ushort4* __restrict__ Y, int n4) {
  const int stride = gridDim.x * blockDim.x;
  for (int i = blockIdx.x * blockDim.x + threadIdx.x; i < n4; i += stride) {
    const float4 v = X[i];
    ushort4 o;
    o.x = f2b(v.x); o.y = f2b(v.y); o.z = f2b(v.z); o.w = f2b(v.w);
    Y[i] = o;
  }
}

// ---- W[nmat][64][64] f32 -> lane-ordered bf16 B-fragments ----
__global__ void wfrag_k(const float* __restrict__ W, u16* __restrict__ fb, int nmat) {
  const int total = nmat * 4096;
  const int stride = gridDim.x * blockDim.x;
  for (int i = blockIdx.x * blockDim.x + threadIdx.x; i < total; i += stride) {
    const int mat = i >> 12, rem = i & 4095;
    const int l = rem >> 6, r = rem & 63;
    const int kc = r >> 5, cb = (r >> 3) & 3, j = r & 7;
    const int k = kc * 32 + ((l >> 4) & 3) * 8 + j;
    const int col = cb * 16 + (l & 15);
    fb[i] = f2b(W[(size_t)mat * 4096 + k * 64 + col]);
  }
}

// ---- MFMA GEMM: Y[N,64] = sum_i X_i[N,64] @ W_i + b  (bf16 I/O, f32 acc) ----
template <int NIN>
__global__ void mfma_g_k(const u16* __restrict__ X0, const u16* __restrict__ X1,
                         const u16* __restrict__ X2,
                         const u16* __restrict__ F0, const u16* __restrict__ F1,
                         const u16* __restrict__ F2,
                         const float* __restrict__ b, u16* __restrict__ Y, int N) {
  const int lane = threadIdx.x & 63;
  const int gw = (blockIdx.x * blockDim.x + threadIdx.x) >> 6;
  const int nw = (gridDim.x * blockDim.x) >> 6;
  const int lo = lane & 15, hi = lane >> 4;
  short8 bf[NIN][2][4];
#pragma unroll
  for (int i = 0; i < NIN; ++i) {
    const u16* Fi = (i == 0) ? F0 : ((i == 1) ? F1 : F2);
#pragma unroll
    for (int kc = 0; kc < 2; ++kc)
#pragma unroll
      for (int cb = 0; cb < 4; ++cb)
        bf[i][kc][cb] = *(const short8*)(Fi + (size_t)lane * 64 + kc * 32 + cb * 8);
  }
  float bcol[4];
#pragma unroll
  for (int cb = 0; cb < 4; ++cb) bcol[cb] = b[cb * 16 + lo];
  const int ntile = (N + 15) >> 4;
  for (int t = gw; t < ntile; t += nw) {
    int arow = t * 16 + lo;
    if (arow >= N) arow = N - 1;
    f32x4 acc[4];
#pragma unroll
    for (int cb = 0; cb < 4; ++cb) {
      acc[cb][0] = bcol[cb]; acc[cb][1] = bcol[cb];
      acc[cb][2] = bcol[cb]; acc[cb][3] = bcol[cb];
    }
#pragma unroll
    for (int i = 0; i < NIN; ++i) {
      const u16* Xi = (i == 0) ? X0 : ((i == 1) ? X1 : X2);
      const short8 a0 = *(const short8*)(Xi + (size_t)arow * 64 + hi * 8);
      const short8 a1 = *(const short8*)(Xi + (size_t)arow * 64 + 32 + hi * 8);
#pragma unroll
      for (int cb = 0; cb < 4; ++cb)
        acc[cb] = __builtin_amdgcn_mfma_f32_16x16x32_bf16(a0, bf[i][0][cb], acc[cb], 0, 0, 0);
#pragma unroll
      for (int cb = 0; cb < 4; ++cb)
        acc[cb] = __builtin_amdgcn_mfma_f32_16x16x32_bf16(a1, bf[i][1][cb], acc[cb], 0, 0, 0);
    }
#pragma unroll
    for (int cb = 0; cb < 4; ++cb) {
#pragma unroll
      for (int j = 0; j < 4; ++j) {
        const int row = t * 16 + hi * 4 + j;
        if (row < N) Y[(size_t)row * 64 + cb * 16 + lo] = f2b(acc[cb][j]);
      }
    }
  }
}

// ---- 2-output MFMA: Y0 = X@W0+b0, Y1 = X@W1+b1 (one X stream) ----
__global__ void mfma_g2_k(const u16* __restrict__ X,
                          const u16* __restrict__ F0, const u16* __restrict__ F1,
                          const float* __restrict__ b0, const float* __restrict__ b1,
                          u16* __restrict__ Y0, u16* __restrict__ Y1, int N) {
  const int lane = threadIdx.x & 63;
  const int gw = (blockIdx.x * blockDim.x + threadIdx.x) >> 6;
  const int nw = (gridDim.x * blockDim.x) >> 6;
  const int lo = lane & 15, hi = lane >> 4;
  short8 bfA[2][4], bfB[2][4];
#pragma unroll
  for (int kc = 0; kc < 2; ++kc)
#pragma unroll
    for (int cb = 0; cb < 4; ++cb) {
      bfA[kc][cb] = *(const short8*)(F0 + (size_t)lane * 64 + kc * 32 + cb * 8);
      bfB[kc][cb] = *(const short8*)(F1 + (size_t)lane * 64 + kc * 32 + cb * 8);
    }
  float bc0[4], bc1[4];
#pragma unroll
  for (int cb = 0; cb < 4; ++cb) { bc0[cb] = b0[cb * 16 + lo]; bc1[cb] = b1[cb * 16 + lo]; }
  const int ntile = (N + 15) >> 4;
  for (int t = gw; t < ntile; t += nw) {
    int arow = t * 16 + lo;
    if (arow >= N) arow = N - 1;
    const short8 a0 = *(const short8*)(X + (size_t)arow * 64 + hi * 8);
    const short8 a1 = *(const short8*)(X + (size_t)arow * 64 + 32 + hi * 8);
    f32x4 accA[4], accB[4];
#pragma unroll
    for (int cb = 0; cb < 4; ++cb) {
      accA[cb][0] = bc0[cb]; accA[cb][1] = bc0[cb]; accA[cb][2] = bc0[cb]; accA[cb][3] = bc0[cb];
      accB[cb][0] = bc1[cb]; accB[cb][1] = bc1[cb]; accB[cb][2] = bc1[cb]; accB[cb][3] = bc1[cb];
    }
#pragma unroll
    for (int cb = 0; cb < 4; ++cb) {
      accA[cb] = __builtin_amdgcn_mfma_f32_16x16x32_bf16(a0, bfA[0][cb], accA[cb], 0, 0, 0);
      accA[cb] = __builtin_amdgcn_mfma_f32_16x16x32_bf16(a1, bfA[1][cb], accA[cb], 0, 0, 0);
      accB[cb] = __builtin_amdgcn_mfma_f32_16x16x32_bf16(a0, bfB[0][cb], accB[cb], 0, 0, 0);
      accB[cb] = __builtin_amdgcn_mfma_f32_16x16x32_bf16(a1, bfB[1][cb], accB[cb], 0, 0, 0);
    }
#pragma unroll
    for (int cb = 0; cb < 4; ++cb) {
#pragma unroll
      for (int j = 0; j < 4; ++j) {
        const int row = t * 16 + hi * 4 + j;
        if (row < N) {
          Y0[(size_t)row * 64 + cb * 16 + lo] = f2b(accA[cb][j]);
          Y1[(size_t)row * 64 + cb * 16 + lo] = f2b(accB[cb][j]);
        }
      }
    }
  }
}

// ========================= CSR build (counting sort) =======================
__global__ void hist_k(const int* __restrict__ key, int* __restrict__ cnt, int E) {
  const int e = blockIdx.x * blockDim.x + threadIdx.x;
  if (e < E) atomicAdd(cnt + key[e], 1);
}

__global__ void scan1_k(const int* __restrict__ in, int* __restrict__ out,
                        int* __restrict__ bsum, int n) {
  __shared__ int tmp[256];
  const int t = threadIdx.x;
  const int base = blockIdx.x * 1024 + t * 4;
  int v0 = (base + 0 < n) ? in[base + 0] : 0;
  int v1 = (base + 1 < n) ? in[base + 1] : 0;
  int v2 = (base + 2 < n) ? in[base + 2] : 0;
  int v3 = (base + 3 < n) ? in[base + 3] : 0;
  const int s = v0 + v1 + v2 + v3;
  tmp[t] = s;
  __syncthreads();
  for (int off = 1; off < 256; off <<= 1) {
    const int x = (t >= off) ? tmp[t - off] : 0;
    __syncthreads();
    tmp[t] += x;
    __syncthreads();
  }
  const int excl = tmp[t] - s;
  if (t == 255) bsum[blockIdx.x] = tmp[255];
  if (base + 0 < n) out[base + 0] = excl;
  if (base + 1 < n) out[base + 1] = excl + v0;
  if (base + 2 < n) out[base + 2] = excl + v0 + v1;
  if (base + 3 < n) out[base + 3] = excl + v0 + v1 + v2;
}
__global__ void scan2_k(int* __restrict__ bsum, int nb) {
  if (threadIdx.x == 0) {
    int acc = 0;
    for (int i = 0; i < nb; ++i) { const int v = bsum[i]; bsum[i] = acc; acc += v; }
  }
}
__global__ void scan3_k(int* __restrict__ out, const int* __restrict__ bsum, int n) {
  const int i = blockIdx.x * blockDim.x + threadIdx.x;
  if (i < n) out[i] += bsum[i >> 10];
}

__global__ void scatter_k(const int* __restrict__ key, const int* __restrict__ other,
                          int* __restrict__ cursor, int* __restrict__ srt, int E) {
  const int e = blockIdx.x * blockDim.x + threadIdx.x;
  if (e < E) {
    const int p = atomicAdd(cursor + key[e], 1);
    srt[p] = other[e];
  }
}

// =================== 32-lane-subwave edge kernels (bf16) ===================
__global__ void gat32_k(const u16* __restrict__ fs, const u16* __restrict__ fd,
                        const float* __restrict__ attn,
                        const int* __restrict__ rowptr, const int* __restrict__ nbr,
                        u16* __restrict__ out, int N) {
  const int lane = threadIdx.x & 63;
  const int l = lane & 31, half = lane >> 5;
  const int wid = (blockIdx.x * blockDim.x + threadIdx.x) >> 6;
  const int nw = (gridDim.x * blockDim.x) >> 6;
  const float awlo = attn[2 * l], awhi = attn[2 * l + 1];
  const uint32* fs32 = (const uint32*)fs;
  const uint32* fd32 = (const uint32*)fd;
  uint32* out32 = (uint32*)out;
  for (int n0 = wid * 2; n0 < N; n0 += nw * 2) {
    const int n = n0 + half;
    const bool act = n < N;
    const int beg = act ? rowptr[n] : 0;
    const int end = act ? rowptr[n + 1] : 0;
    float fdlo = 0.0f, fdhi = 0.0f;
    if (act) {
      const uint32 fp = fd32[(size_t)n * 32 + l];
      fdlo = blo(fp); fdhi = bhi(fp);
    }
    float aclo = 0.0f, achi = 0.0f, den = 0.0f;
    int e = beg;
    for (; e + 1 < end; e += 2) {
      const int s0 = nbr[e], s1 = nbr[e + 1];
      const uint32 f0 = fs32[(size_t)s0 * 32 + l];
      const uint32 f1 = fs32[(size_t)s1 * 32 + l];
      const float f0l = blo(f0), f0h = bhi(f0);
      const float f1l = blo(f1), f1h = bhi(f1);
      float v0l = f0l + fdlo; v0l = v0l > 0.0f ? v0l : LRELU_SLOPE * v0l;
      float v0h = f0h + fdhi; v0h = v0h > 0.0f ? v0h : LRELU_SLOPE * v0h;
      float v1l = f1l + fdlo; v1l = v1l > 0.0f ? v1l : LRELU_SLOPE * v1l;
      float v1h = f1h + fdhi; v1h = v1h > 0.0f ? v1h : LRELU_SLOPE * v1h;
      float p0 = fmaf(v0l, awlo, v0h * awhi);
      float p1 = fmaf(v1l, awlo, v1h * awhi);
#pragma unroll
      for (int o = 16; o; o >>= 1) {
        p0 += __shfl_xor(p0, o, 64);
        p1 += __shfl_xor(p1, o, 64);
      }
      const float e0 = __expf(p0), e1 = __expf(p1);
      den += e0 + e1;
      aclo = fmaf(e0, f0l, aclo); achi = fmaf(e0, f0h, achi);
      aclo = fmaf(e1, f1l, aclo); achi = fmaf(e1, f1h, achi);
    }
    if (e < end) {
      const int s0 = nbr[e];
      const uint32 f0 = fs32[(size_t)s0 * 32 + l];
      const float f0l = blo(f0), f0h = bhi(f0);
      float v0l = f0l + fdlo; v0l = v0l > 0.0f ? v0l : LRELU_SLOPE * v0l;
      float v0h = f0h + fdhi; v0h = v0h > 0.0f ? v0h : LRELU_SLOPE * v0h;
      float p0 = fmaf(v0l, awlo, v0h * awhi);
#pragma unroll
      for (int o = 16; o; o >>= 1) p0 += __shfl_xor(p0, o, 64);
      const float e0 = __expf(p0);
      den += e0;
      aclo = fmaf(e0, f0l, aclo); achi = fmaf(e0, f0h, achi);
    }
    const float inv = den > 0.0f ? 1.0f / den : 0.0f;
    if (act) out32[(size_t)n * 32 + l] = packb(aclo * inv, achi * inv);
  }
}

template <int MODE>
__global__ void cheb32_k(const u16* __restrict__ x, const u16* __restrict__ T0,
                         const u16* __restrict__ Tp, const float* __restrict__ dinv,
                         const float* __restrict__ lam,
                         const int* __restrict__ rowptr, const int* __restrict__ nbr,
                         u16* __restrict__ outT, int N) {
  const float re = 2.0f / lam[0];
  const int lane = threadIdx.x & 63;
  const int l = lane & 31, half = lane >> 5;
  const int wid = (blockIdx.x * blockDim.x + threadIdx.x) >> 6;
  const int nw = (gridDim.x * blockDim.x) >> 6;
  const uint32* x32 = (const uint32*)x;
  const uint32* T032 = (const uint32*)T0;
  const uint32* Tp32 = (const uint32*)Tp;
  uint32* o32 = (uint32*)outT;
  for (int n0 = wid * 2; n0 < N; n0 += nw * 2) {
    const int n = n0 + half;
    const bool act = n < N;
    const int beg = act ? rowptr[n] : 0;
    const int end = act ? rowptr[n + 1] : 0;
    float aclo = 0.0f, achi = 0.0f;
    int e = beg;
    for (; e + 1 < end; e += 2) {
      const int s0 = nbr[e], s1 = nbr[e + 1];
      const uint32 f0 = x32[(size_t)s0 * 32 + l];
      const uint32 f1 = x32[(size_t)s1 * 32 + l];
      const float d0 = dinv[s0], d1 = dinv[s1];
      aclo = fmaf(blo(f0), d0, aclo); achi = fmaf(bhi(f0), d0, achi);
      aclo = fmaf(blo(f1), d1, aclo); achi = fmaf(bhi(f1), d1, achi);
    }
    if (e < end) {
      const int s0 = nbr[e];
      const uint32 f0 = x32[(size_t)s0 * 32 + l];
      const float d0 = dinv[s0];
      aclo = fmaf(blo(f0), d0, aclo); achi = fmaf(bhi(f0), d0, achi);
    }
    if (!act) continue;
    const float dn = dinv[n];
    const float hl = aclo * dn, hh = achi * dn;
    float rl, rh;
    if (MODE == 1) {
      const uint32 t0 = T032[(size_t)n * 32 + l];
      rl = -re * hl + (re - 1.0f) * blo(t0);
      rh = -re * hh + (re - 1.0f) * bhi(t0);
    } else {
      const uint32 t0 = T032[(size_t)n * 32 + l];
      const uint32 tp = Tp32[(size_t)n * 32 + l];
      rl = -2.0f * re * hl + 2.0f * (re - 1.0f) * blo(tp) - blo(t0);
      rh = -2.0f * re * hh + 2.0f * (re - 1.0f) * bhi(tp) - bhi(t0);
    }
    o32[(size_t)n * 32 + l] = packb(rl, rh);
  }
}

__global__ void dinv_k(const int* __restrict__ rowptr, float* __restrict__ dinv, int N) {
  const int i = blockIdx.x * blockDim.x + threadIdx.x;
  if (i < N) {
    const float deg = (float)(rowptr[i + 1] - rowptr[i]);
    dinv[i] = rsqrtf(fmaxf(deg, 1.0f));
  }
}

// ---- mutualistic (bf16 I/O) ----
__global__ void mut_k(const u16* __restrict__ hP, const u16* __restrict__ hS,
                      u16* __restrict__ mP, u16* __restrict__ mS, int N) {
  const int lane = threadIdx.x & 63;
  const int u = (blockIdx.x * blockDim.x + threadIdx.x) >> 6;
  if (u >= N) return;
  const float p = b2f(hP[(size_t)u * 64 + lane]);
  const float s = b2f(hS[(size_t)u * 64 + lane]);
  const float m = p * s;
  float mxp = p, mxs = s;
#pragma unroll
  for (int o = 32; o; o >>= 1) {
    mxp = fmaxf(mxp, __shfl_xor(mxp, o, 64));
    mxs = fmaxf(mxs, __shfl_xor(mxs, o, 64));
  }
  const float ep = __expf(p - mxp);
  const float es = __expf(s - mxs);
  float sp = ep, ss = es;
#pragma unroll
  for (int o = 32; o; o >>= 1) {
    sp += __shfl_xor(sp, o, 64);
    ss += __shfl_xor(ss, o, 64);
  }
  mP[(size_t)u * 64 + lane] = f2b(m * (ep / sp));
  mS[(size_t)u * 64 + lane] = f2b(m * (es / ss));
}

// ---- edge dot: 4 edges/iter (2 halves x ILP-2), packed bf16 math ----
__global__ void dot32_k(const u16* __restrict__ A, const u16* __restrict__ Bm,
                        const int* __restrict__ src, const int* __restrict__ dst,
                        float* __restrict__ out, int E) {
  const int lane = threadIdx.x & 63;
  const int l = lane & 31, half = lane >> 5;
  const int wid = (blockIdx.x * blockDim.x + threadIdx.x) >> 6;
  const int nw = (gridDim.x * blockDim.x) >> 6;
  const uint32* A32 = (const uint32*)A;
  const uint32* B32 = (const uint32*)Bm;
  for (int e0 = wid * 4; e0 < E; e0 += nw * 4) {
    const int eA = e0 + half;
    const int eB = e0 + 2 + half;
    const int eAc = eA < E ? eA : E - 1;
    const int eBc = eB < E ? eB : E - 1;
    const int sA = src[eAc], dA = dst[eAc];
    const int sB = src[eBc], dB = dst[eBc];
    const uint32 a0 = A32[(size_t)sA * 32 + l];
    const uint32 b0 = B32[(size_t)dA * 32 + l];
    const uint32 a1 = A32[(size_t)sB * 32 + l];
    const uint32 b1 = B32[(size_t)dB * 32 + l];
    float p0 = fmaf(blo(a0), blo(b0), bhi(a0) * bhi(b0));
    float p1 = fmaf(blo(a1), blo(b1), bhi(a1) * bhi(b1));
#pragma unroll
    for (int o = 16; o; o >>= 1) {
      p0 += __shfl_xor(p0, o, 64);
      p1 += __shfl_xor(p1, o, 64);
    }
    if (l == 0) {
      if (eA < E) out[eA] = p0;
      if (eB < E) out[eB] = p1;
    }
  }
}

// ---------------------------------------------------------------------------

static void build_csr(const int* key, const int* other, int E, int N,
                      int* rowptr, int* srt, int* cursor, int* bsum,
                      hipStream_t stream) {
  const int n1 = N + 1;
  hipMemsetAsync(cursor, 0, (size_t)n1 * 4, stream);
  hist_k<<<(E + 255) / 256, 256, 0, stream>>>(key, cursor, E);
  const int nb = (n1 + 1023) / 1024;
  scan1_k<<<nb, 256, 0, stream>>>(cursor, rowptr, bsum, n1);
  scan2_k<<<1, 64, 0, stream>>>(bsum, nb);
  scan3_k<<<(n1 + 255) / 256, 256, 0, stream>>>(rowptr, bsum, n1);
  hipMemcpyAsync(cursor, rowptr, (size_t)N * 4, hipMemcpyDeviceToDevice, stream);
  scatter_k<<<(E + 255) / 256, 256, 0, stream>>>(key, other, cursor, srt, E);
}

extern "C" void kernel_launch(void* const* d_in, const int* in_sizes, int n_in,
                              void* d_out, int out_size, void* d_ws, size_t ws_size,
                              hipStream_t stream) {
  const float* user_emb = (const float*)d_in[0];
  const float* item_emb = (const float*)d_in[1];
  const int* rate_src = (const int*)d_in[2];
  const int* rate_dst = (const int*)d_in[3];
  const int* link_src = (const int*)d_in[4];
  const int* link_dst = (const int*)d_in[5];
  const int* neg_rate_src = (const int*)d_in[6];
  const int* neg_rate_dst = (const int*)d_in[7];
  const int* neg_link_src = (const int*)d_in[8];
  const int* neg_link_dst = (const int*)d_in[9];
  const float* lam = (const float*)d_in[10];
  const float* gat_Wsrc = (const float*)d_in[11];
  const float* gat_bsrc = (const float*)d_in[12];
  const float* gat_Wdst = (const float*)d_in[13];
  const float* gat_bdst = (const float*)d_in[14];
  const float* gat_attn = (const float*)d_in[15];
  const float* W_out = (const float*)d_in[16];
  const float* b_out = (const float*)d_in[17];
  const float* cheb_W = (const float*)d_in[18];
  const float* cheb_b = (const float*)d_in[19];
  const float* Wc = (const float*)d_in[20];
  const float* bc = (const float*)d_in[21];
  const float* Wsm = (const float*)d_in[22];
  const float* bs = (const float*)d_in[23];
  const float* WpP = (const float*)d_in[24];
  const float* bpP = (const float*)d_in[25];
  const float* WpS = (const float*)d_in[26];
  const float* bpS = (const float*)d_in[27];

  const int NU = in_sizes[0] / 64;
  const int NI = in_sizes[1] / 64;
  const int NR = in_sizes[2];
  const int NL = in_sizes[4];
  const int NMAX = NU > NI ? NU : NI;
  const size_t MAT = (size_t)NMAX * 64;
  const int FR = 4096;

  u16* ub = (u16*)d_ws;
  u16* ib = ub + (size_t)NU * 64;
  u16* B0 = ib + (size_t)NI * 64;
  u16* B1 = B0 + MAT;
  u16* B2 = B1 + MAT;
  u16* B3 = B2 + MAT;
  u16* B4 = B3 + MAT;
  u16* B5 = B4 + MAT;
  u16* B6 = B5 + MAT;
  u16* B7 = B6 + MAT;
  u16* fb = B7 + MAT;
  u16* fbWsrc = fb;
  u16* fbWdst = fb + 5 * FR;
  u16* fbWout = fb + 10 * FR;
  u16* fbCheb = fb + 12 * FR;
  u16* fbWc = fb + 15 * FR;
  u16* fbWsm = fb + 17 * FR;
  u16* fbWpP = fb + 19 * FR;
  u16* fbWpS = fb + 21 * FR;
  int* ip = (int*)(fb + 23 * FR);
  int* rp_rd = ip;
  int* rp_rs = rp_rd + (NI + 1);
  int* rp_ld = rp_rs + (NU + 1);
  int* srt_rd = rp_ld + (NU + 1);
  int* srt_rs = srt_rd + NR;
  int* srt_ld = srt_rs + NR;
  int* cursor = srt_ld + NL;
  int* bsum = cursor + (NMAX + 1);
  float* dinv = (float*)(bsum + 256);

  const int B64 = 64;

  // ---- bf16 copies + W fragment prep ----
  cvt_k<<<1024, 256, 0, stream>>>((const float4*)user_emb, (ushort4*)ub, NU * 16);
  cvt_k<<<1024, 256, 0, stream>>>((const float4*)item_emb, (ushort4*)ib, NI * 16);
  wfrag_k<<<20, 256, 0, stream>>>(gat_Wsrc, fbWsrc, 5);
  wfrag_k<<<20, 256, 0, stream>>>(gat_Wdst, fbWdst, 5);
  wfrag_k<<<8, 256, 0, stream>>>(W_out, fbWout, 2);
  wfrag_k<<<12, 256, 0, stream>>>(cheb_W, fbCheb, 3);
  wfrag_k<<<8, 256, 0, stream>>>(Wc, fbWc, 2);
  wfrag_k<<<8, 256, 0, stream>>>(Wsm, fbWsm, 2);
  wfrag_k<<<8, 256, 0, stream>>>(WpP, fbWpP, 2);
  wfrag_k<<<8, 256, 0, stream>>>(WpS, fbWpS, 2);

  // ---- 3 CSR groupings (independent passes; fused scatter2 regressed) ----
  build_csr(rate_dst, rate_src, NR, NI, rp_rd, srt_rd, cursor, bsum, stream);
  build_csr(rate_src, rate_dst, NR, NU, rp_rs, srt_rs, cursor, bsum, stream);
  build_csr(link_dst, link_src, NL, NU, rp_ld, srt_ld, cursor, bsum, stream);

  // ---- projections (2-output MFMA): fs0->B0, fd1->B1 ; fd2->B2, fd3->B3 ----
  mfma_g2_k<<<MFMA_BLOCKS, 256, 0, stream>>>(ub, fbWsrc + 0 * FR, fbWdst + 1 * FR,
      gat_bsrc + 0 * B64, gat_bdst + 1 * B64, B0, B1, NU);
  mfma_g2_k<<<MFMA_BLOCKS, 256, 0, stream>>>(ub, fbWdst + 2 * FR, fbWdst + 3 * FR,
      gat_bdst + 2 * B64, gat_bdst + 3 * B64, B2, B3, NU);
  // ---- item projections: fd0->B4, fs1->B5 ----
  mfma_g2_k<<<MFMA_BLOCKS, 256, 0, stream>>>(ib, fbWdst + 0 * FR, fbWsrc + 1 * FR,
      gat_bdst + 0 * B64, gat_bsrc + 1 * B64, B4, B5, NI);

  // ---- gat0 -> B6 (h1_item) ; gat1 -> B7 (h2_user) ----
  gat32_k<<<EDGE_BLOCKS, 256, 0, stream>>>(B0, B4, gat_attn + 0 * B64, rp_rd, srt_rd, B6, NI);
  gat32_k<<<EDGE_BLOCKS, 256, 0, stream>>>(B5, B1, gat_attn + 1 * B64, rp_rs, srt_rs, B7, NU);

  // ---- fs2 = h1_item @ Ws2 -> B0 ; gat2 -> B4 (item_infl) ----
  mfma_g_k<1><<<MFMA_BLOCKS, 256, 0, stream>>>(B6, nullptr, nullptr,
      fbWsrc + 2 * FR, nullptr, nullptr, gat_bsrc + 2 * B64, B0, NI);
  gat32_k<<<EDGE_BLOCKS, 256, 0, stream>>>(B0, B2, gat_attn + 2 * B64, rp_rs, srt_rs, B4, NU);

  // ---- fs3 = h2_user @ Ws3 -> B5 ; gat3 -> B2 (social_item) ----
  mfma_g_k<1><<<MFMA_BLOCKS, 256, 0, stream>>>(B7, nullptr, nullptr,
      fbWsrc + 3 * FR, nullptr, nullptr, gat_bsrc + 3 * B64, B5, NU);
  gat32_k<<<EDGE_BLOCKS, 256, 0, stream>>>(B5, B3, gat_attn + 3 * B64, rp_ld, srt_ld, B2, NU);

  // ---- user_pref = [item_infl(B4), social_item(B2)] @ W_out -> B0 ----
  mfma_g_k<2><<<MFMA_BLOCKS, 256, 0, stream>>>(B4, B2, nullptr,
      fbWout + 0 * FR, fbWout + 1 * FR, nullptr, b_out, B0, NU);

  // ---- ChebConv(k=3): T1->B5, T2->B3, rst->B6 ----
  dinv_k<<<(NU + 255) / 256, 256, 0, stream>>>(rp_ld, dinv, NU);
  cheb32_k<1><<<EDGE_BLOCKS, 256, 0, stream>>>(ub, ub, nullptr, dinv, lam,
                                               rp_ld, srt_ld, B5, NU);
  cheb32_k<2><<<EDGE_BLOCKS, 256, 0, stream>>>(B5, ub, B5, dinv, lam,
                                               rp_ld, srt_ld, B3, NU);
  mfma_g_k<3><<<MFMA_BLOCKS, 256, 0, stream>>>(ub, B5, B3,
      fbCheb + 0 * FR, fbCheb + 1 * FR, fbCheb + 2 * FR, cheb_b, B6, NU);

  // ---- rst projections: fs4->B4, fd4->B2 ; gat4 -> B5 (user_social) ----
  mfma_g2_k<<<MFMA_BLOCKS, 256, 0, stream>>>(B6, fbWsrc + 4 * FR, fbWdst + 4 * FR,
      gat_bsrc + 4 * B64, gat_bdst + 4 * B64, B4, B2, NU);
  gat32_k<<<EDGE_BLOCKS, 256, 0, stream>>>(B4, B2, gat_attn + 4 * B64, rp_ld, srt_ld, B5, NU);

  // ---- mutualistic: h_uP->B4, h_uS->B2 ----
  mfma_g_k<2><<<MFMA_BLOCKS, 256, 0, stream>>>(B0, ub, nullptr,
      fbWc + 0 * FR, fbWc + 1 * FR, nullptr, bc, B4, NU);
  mfma_g_k<2><<<MFMA_BLOCKS, 256, 0, stream>>>(B5, ub, nullptr,
      fbWsm + 0 * FR, fbWsm + 1 * FR, nullptr, bs, B2, NU);
  mut_k<<<(NU + 3) / 4, 256, 0, stream>>>(B4, B2, B3, B7, NU);  // mP->B3, mS->B7
  mfma_g_k<2><<<MFMA_BLOCKS, 256, 0, stream>>>(B3, B4, nullptr,
      fbWpP + 0 * FR, fbWpP + 1 * FR, nullptr, bpP, B0, NU);
  mfma_g_k<2><<<MFMA_BLOCKS, 256, 0, stream>>>(B7, B2, nullptr,
      fbWpS + 0 * FR, fbWpS + 1 * FR, nullptr, bpS, B5, NU);

  // ---- predictors ----
  float* out = (float*)d_out;
  dot32_k<<<EDGE_BLOCKS, 256, 0, stream>>>(B0, ib, rate_src, rate_dst, out, NR);
  dot32_k<<<EDGE_BLOCKS, 256, 0, stream>>>(B0, ib, neg_rate_src, neg_rate_dst, out + NR, NR);
  dot32_k<<<EDGE_BLOCKS, 256, 0, stream>>>(B5, ub, link_src, link_dst, out + 2 * (size_t)NR, NL);
  dot32_k<<<EDGE_BLOCKS, 256, 0, stream>>>(B5, ub, neg_link_src, neg_link_dst, out + 2 * (size_t)NR + NL, NL);
}

// Round 18
// 992.692 us; speedup vs baseline: 1.0612x; 1.0244x over previous
//
#include <hip/hip_runtime.h>

// ---------------------------------------------------------------------------
// MutualRec forward: 5x GATv2 + ChebConv(k=3) + mutualistic MLP + edge dots
// R18: launch/pass overhead sweep on R17:
//   - wfrag_all_k: all 23 W mats fragmented in one launch (was 8)
//   - cvt2_k: both embedding tables in one launch
//   - gat12_k: gat1+gat2 fused over one rp_rs pass (shared nbr stream)
//   - mfma_pair_k / dot_pair_k: independent jobs via BLOCK split (no
//     per-thread fusion of random-access chains; R16 lesson)
// ---------------------------------------------------------------------------

#define LRELU_SLOPE 0.2f
#define MFMA_BLOCKS 1024
#define EDGE_BLOCKS 2048

typedef unsigned short u16;
typedef unsigned int uint32;
typedef __attribute__((ext_vector_type(8))) short short8;
typedef __attribute__((ext_vector_type(4))) float f32x4;

__device__ __forceinline__ float b2f(u16 u) {
  return __uint_as_float(((uint32)u) << 16);
}
__device__ __forceinline__ u16 f2b(float f) {
  uint32 u = __float_as_uint(f);
  uint32 r = (u + 0x7fffu + ((u >> 16) & 1u)) >> 16;
  return (u16)r;
}
__device__ __forceinline__ float blo(uint32 p) { return __uint_as_float(p << 16); }
__device__ __forceinline__ float bhi(uint32 p) { return __uint_as_float(p & 0xffff0000u); }
__device__ __forceinline__ uint32 packb(float lo, float hi) {
  return (uint32)f2b(lo) | ((uint32)f2b(hi) << 16);
}

// ---- f32 -> bf16: both tables, one launch ----
__global__ void cvt2_k(const float4* __restrict__ A, ushort4* __restrict__ Ya, int n4a,
                       const float4* __restrict__ B, ushort4* __restrict__ Yb, int n4b) {
  const int stride = gridDim.x * blockDim.x;
  const int total = n4a + n4b;
  for (int i = blockIdx.x * blockDim.x + threadIdx.x; i < total; i += stride) {
    const bool first = i < n4a;
    const float4 v = first ? A[i] : B[i - n4a];
    ushort4 o;
    o.x = f2b(v.x); o.y = f2b(v.y); o.z = f2b(v.z); o.w = f2b(v.w);
    if (first) Ya[i] = o; else Yb[i - n4a] = o;
  }
}

// ---- all 23 W mats -> lane-ordered bf16 B-fragments, one launch ----
// fb layout: [Wsrc x5][Wdst x5][Wout x2][cheb x3][Wc x2][Wsm x2][WpP x2][WpS x2]
__global__ void wfrag_all_k(const float* __restrict__ Wsrc, const float* __restrict__ Wdst,
                            const float* __restrict__ Wout, const float* __restrict__ Wch,
                            const float* __restrict__ Wc, const float* __restrict__ Wsm,
                            const float* __restrict__ WpP, const float* __restrict__ WpS,
                            u16* __restrict__ fb) {
  const int total = 23 * 4096;
  const int stride = gridDim.x * blockDim.x;
  for (int i = blockIdx.x * blockDim.x + threadIdx.x; i < total; i += stride) {
    const int mat = i >> 12, rem = i & 4095;
    const float* W;
    int m;
    if (mat < 5)       { W = Wsrc; m = mat; }
    else if (mat < 10) { W = Wdst; m = mat - 5; }
    else if (mat < 12) { W = Wout; m = mat - 10; }
    else if (mat < 15) { W = Wch;  m = mat - 12; }
    else if (mat < 17) { W = Wc;   m = mat - 15; }
    else if (mat < 19) { W = Wsm;  m = mat - 17; }
    else if (mat < 21) { W = WpP;  m = mat - 19; }
    else               { W = WpS;  m = mat - 21; }
    const int l = rem >> 6, r = rem & 63;
    const int kc = r >> 5, cb = (r >> 3) & 3, j = r & 7;
    const int k = kc * 32 + ((l >> 4) & 3) * 8 + j;
    const int col = cb * 16 + (l & 15);
    fb[i] = f2b(W[(size_t)m * 4096 + k * 64 + col]);
  }
}

// ---- MFMA GEMM: Y[N,64] = sum_i X_i[N,64] @ W_i + b  (bf16 I/O, f32 acc) ----
template <int NIN>
__device__ __forceinline__ void mfma_body(const u16* X0, const u16* X1, const u16* X2,
                                          const u16* F0, const u16* F1, const u16* F2,
                                          const float* b, u16* Y, int N,
                                          int gw, int nw, int lane) {
  const int lo = lane & 15, hi = lane >> 4;
  short8 bf[NIN][2][4];
#pragma unroll
  for (int i = 0; i < NIN; ++i) {
    const u16* Fi = (i == 0) ? F0 : ((i == 1) ? F1 : F2);
#pragma unroll
    for (int kc = 0; kc < 2; ++kc)
#pragma unroll
      for (int cb = 0; cb < 4; ++cb)
        bf[i][kc][cb] = *(const short8*)(Fi + (size_t)lane * 64 + kc * 32 + cb * 8);
  }
  float bcol[4];
#pragma unroll
  for (int cb = 0; cb < 4; ++cb) bcol[cb] = b[cb * 16 + lo];
  const int ntile = (N + 15) >> 4;
  for (int t = gw; t < ntile; t += nw) {
    int arow = t * 16 + lo;
    if (arow >= N) arow = N - 1;
    f32x4 acc[4];
#pragma unroll
    for (int cb = 0; cb < 4; ++cb) {
      acc[cb][0] = bcol[cb]; acc[cb][1] = bcol[cb];
      acc[cb][2] = bcol[cb]; acc[cb][3] = bcol[cb];
    }
#pragma unroll
    for (int i = 0; i < NIN; ++i) {
      const u16* Xi = (i == 0) ? X0 : ((i == 1) ? X1 : X2);
      const short8 a0 = *(const short8*)(Xi + (size_t)arow * 64 + hi * 8);
      const short8 a1 = *(const short8*)(Xi + (size_t)arow * 64 + 32 + hi * 8);
#pragma unroll
      for (int cb = 0; cb < 4; ++cb)
        acc[cb] = __builtin_amdgcn_mfma_f32_16x16x32_bf16(a0, bf[i][0][cb], acc[cb], 0, 0, 0);
#pragma unroll
      for (int cb = 0; cb < 4; ++cb)
        acc[cb] = __builtin_amdgcn_mfma_f32_16x16x32_bf16(a1, bf[i][1][cb], acc[cb], 0, 0, 0);
    }
#pragma unroll
    for (int cb = 0; cb < 4; ++cb) {
#pragma unroll
      for (int j = 0; j < 4; ++j) {
        const int row = t * 16 + hi * 4 + j;
        if (row < N) Y[(size_t)row * 64 + cb * 16 + lo] = f2b(acc[cb][j]);
      }
    }
  }
}

template <int NIN>
__global__ void mfma_g_k(const u16* __restrict__ X0, const u16* __restrict__ X1,
                         const u16* __restrict__ X2,
                         const u16* __restrict__ F0, const u16* __restrict__ F1,
                         const u16* __restrict__ F2,
                         const float* __restrict__ b, u16* __restrict__ Y, int N) {
  const int lane = threadIdx.x & 63;
  const int gw = (blockIdx.x * blockDim.x + threadIdx.x) >> 6;
  const int nw = (gridDim.x * blockDim.x) >> 6;
  mfma_body<NIN>(X0, X1, X2, F0, F1, F2, b, Y, N, gw, nw, lane);
}

// ---- 2-output MFMA: Y0 = X@W0+b0, Y1 = X@W1+b1 (one X stream) ----
__global__ void mfma_g2_k(const u16* __restrict__ X,
                          const u16* __restrict__ F0, const u16* __restrict__ F1,
                          const float* __restrict__ b0, const float* __restrict__ b1,
                          u16* __restrict__ Y0, u16* __restrict__ Y1, int N) {
  const int lane = threadIdx.x & 63;
  const int gw = (blockIdx.x * blockDim.x + threadIdx.x) >> 6;
  const int nw = (gridDim.x * blockDim.x) >> 6;
  const int lo = lane & 15, hi = lane >> 4;
  short8 bfA[2][4], bfB[2][4];
#pragma unroll
  for (int kc = 0; kc < 2; ++kc)
#pragma unroll
    for (int cb = 0; cb < 4; ++cb) {
      bfA[kc][cb] = *(const short8*)(F0 + (size_t)lane * 64 + kc * 32 + cb * 8);
      bfB[kc][cb] = *(const short8*)(F1 + (size_t)lane * 64 + kc * 32 + cb * 8);
    }
  float bc0[4], bc1[4];
#pragma unroll
  for (int cb = 0; cb < 4; ++cb) { bc0[cb] = b0[cb * 16 + lo]; bc1[cb] = b1[cb * 16 + lo]; }
  const int ntile = (N + 15) >> 4;
  for (int t = gw; t < ntile; t += nw) {
    int arow = t * 16 + lo;
    if (arow >= N) arow = N - 1;
    const short8 a0 = *(const short8*)(X + (size_t)arow * 64 + hi * 8);
    const short8 a1 = *(const short8*)(X + (size_t)arow * 64 + 32 + hi * 8);
    f32x4 accA[4], accB[4];
#pragma unroll
    for (int cb = 0; cb < 4; ++cb) {
      accA[cb][0] = bc0[cb]; accA[cb][1] = bc0[cb]; accA[cb][2] = bc0[cb]; accA[cb][3] = bc0[cb];
      accB[cb][0] = bc1[cb]; accB[cb][1] = bc1[cb]; accB[cb][2] = bc1[cb]; accB[cb][3] = bc1[cb];
    }
#pragma unroll
    for (int cb = 0; cb < 4; ++cb) {
      accA[cb] = __builtin_amdgcn_mfma_f32_16x16x32_bf16(a0, bfA[0][cb], accA[cb], 0, 0, 0);
      accA[cb] = __builtin_amdgcn_mfma_f32_16x16x32_bf16(a1, bfA[1][cb], accA[cb], 0, 0, 0);
      accB[cb] = __builtin_amdgcn_mfma_f32_16x16x32_bf16(a0, bfB[0][cb], accB[cb], 0, 0, 0);
      accB[cb] = __builtin_amdgcn_mfma_f32_16x16x32_bf16(a1, bfB[1][cb], accB[cb], 0, 0, 0);
    }
#pragma unroll
    for (int cb = 0; cb < 4; ++cb) {
#pragma unroll
      for (int j = 0; j < 4; ++j) {
        const int row = t * 16 + hi * 4 + j;
        if (row < N) {
          Y0[(size_t)row * 64 + cb * 16 + lo] = f2b(accA[cb][j]);
          Y1[(size_t)row * 64 + cb * 16 + lo] = f2b(accB[cb][j]);
        }
      }
    }
  }
}

// ---- two independent NIN=2 GEMMs, block-split grid ----
__global__ void mfma_pair_k(const u16* __restrict__ Xa0, const u16* __restrict__ Xa1,
                            const u16* __restrict__ Fa0, const u16* __restrict__ Fa1,
                            const float* __restrict__ ba, u16* __restrict__ Ya, int Na,
                            const u16* __restrict__ Xb0, const u16* __restrict__ Xb1,
                            const u16* __restrict__ Fb0, const u16* __restrict__ Fb1,
                            const float* __restrict__ bb, u16* __restrict__ Yb, int Nb) {
  const int lane = threadIdx.x & 63;
  const int halfg = gridDim.x >> 1;
  const bool jobA = (int)blockIdx.x < halfg;
  const int bid = jobA ? blockIdx.x : blockIdx.x - halfg;
  const int gw = (bid * blockDim.x + threadIdx.x) >> 6;
  const int nw = (halfg * blockDim.x) >> 6;
  if (jobA) mfma_body<2>(Xa0, Xa1, nullptr, Fa0, Fa1, nullptr, ba, Ya, Na, gw, nw, lane);
  else      mfma_body<2>(Xb0, Xb1, nullptr, Fb0, Fb1, nullptr, bb, Yb, Nb, gw, nw, lane);
}

// ========================= CSR build (counting sort) =======================
__global__ void hist_k(const int* __restrict__ key, int* __restrict__ cnt, int E) {
  const int e = blockIdx.x * blockDim.x + threadIdx.x;
  if (e < E) atomicAdd(cnt + key[e], 1);
}

__global__ void scan1_k(const int* __restrict__ in, int* __restrict__ out,
                        int* __restrict__ bsum, int n) {
  __shared__ int tmp[256];
  const int t = threadIdx.x;
  const int base = blockIdx.x * 1024 + t * 4;
  int v0 = (base + 0 < n) ? in[base + 0] : 0;
  int v1 = (base + 1 < n) ? in[base + 1] : 0;
  int v2 = (base + 2 < n) ? in[base + 2] : 0;
  int v3 = (base + 3 < n) ? in[base + 3] : 0;
  const int s = v0 + v1 + v2 + v3;
  tmp[t] = s;
  __syncthreads();
  for (int off = 1; off < 256; off <<= 1) {
    const int x = (t >= off) ? tmp[t - off] : 0;
    __syncthreads();
    tmp[t] += x;
    __syncthreads();
  }
  const int excl = tmp[t] - s;
  if (t == 255) bsum[blockIdx.x] = tmp[255];
  if (base + 0 < n) out[base + 0] = excl;
  if (base + 1 < n) out[base + 1] = excl + v0;
  if (base + 2 < n) out[base + 2] = excl + v0 + v1;
  if (base + 3 < n) out[base + 3] = excl + v0 + v1 + v2;
}
__global__ void scan2_k(int* __restrict__ bsum, int nb) {
  if (threadIdx.x == 0) {
    int acc = 0;
    for (int i = 0; i < nb; ++i) { const int v = bsum[i]; bsum[i] = acc; acc += v; }
  }
}
__global__ void scan3_k(int* __restrict__ out, const int* __restrict__ bsum, int n) {
  const int i = blockIdx.x * blockDim.x + threadIdx.x;
  if (i < n) out[i] += bsum[i >> 10];
}

__global__ void scatter_k(const int* __restrict__ key, const int* __restrict__ other,
                          int* __restrict__ cursor, int* __restrict__ srt, int E) {
  const int e = blockIdx.x * blockDim.x + threadIdx.x;
  if (e < E) {
    const int p = atomicAdd(cursor + key[e], 1);
    srt[p] = other[e];
  }
}

// =================== 32-lane-subwave edge kernels (bf16) ===================
__global__ void gat32_k(const u16* __restrict__ fs, const u16* __restrict__ fd,
                        const float* __restrict__ attn,
                        const int* __restrict__ rowptr, const int* __restrict__ nbr,
                        u16* __restrict__ out, int N) {
  const int lane = threadIdx.x & 63;
  const int l = lane & 31, half = lane >> 5;
  const int wid = (blockIdx.x * blockDim.x + threadIdx.x) >> 6;
  const int nw = (gridDim.x * blockDim.x) >> 6;
  const float awlo = attn[2 * l], awhi = attn[2 * l + 1];
  const uint32* fs32 = (const uint32*)fs;
  const uint32* fd32 = (const uint32*)fd;
  uint32* out32 = (uint32*)out;
  for (int n0 = wid * 2; n0 < N; n0 += nw * 2) {
    const int n = n0 + half;
    const bool act = n < N;
    const int beg = act ? rowptr[n] : 0;
    const int end = act ? rowptr[n + 1] : 0;
    float fdlo = 0.0f, fdhi = 0.0f;
    if (act) {
      const uint32 fp = fd32[(size_t)n * 32 + l];
      fdlo = blo(fp); fdhi = bhi(fp);
    }
    float aclo = 0.0f, achi = 0.0f, den = 0.0f;
    int e = beg;
    for (; e + 1 < end; e += 2) {
      const int s0 = nbr[e], s1 = nbr[e + 1];
      const uint32 f0 = fs32[(size_t)s0 * 32 + l];
      const uint32 f1 = fs32[(size_t)s1 * 32 + l];
      const float f0l = blo(f0), f0h = bhi(f0);
      const float f1l = blo(f1), f1h = bhi(f1);
      float v0l = f0l + fdlo; v0l = v0l > 0.0f ? v0l : LRELU_SLOPE * v0l;
      float v0h = f0h + fdhi; v0h = v0h > 0.0f ? v0h : LRELU_SLOPE * v0h;
      float v1l = f1l + fdlo; v1l = v1l > 0.0f ? v1l : LRELU_SLOPE * v1l;
      float v1h = f1h + fdhi; v1h = v1h > 0.0f ? v1h : LRELU_SLOPE * v1h;
      float p0 = fmaf(v0l, awlo, v0h * awhi);
      float p1 = fmaf(v1l, awlo, v1h * awhi);
#pragma unroll
      for (int o = 16; o; o >>= 1) {
        p0 += __shfl_xor(p0, o, 64);
        p1 += __shfl_xor(p1, o, 64);
      }
      const float e0 = __expf(p0), e1 = __expf(p1);
      den += e0 + e1;
      aclo = fmaf(e0, f0l, aclo); achi = fmaf(e0, f0h, achi);
      aclo = fmaf(e1, f1l, aclo); achi = fmaf(e1, f1h, achi);
    }
    if (e < end) {
      const int s0 = nbr[e];
      const uint32 f0 = fs32[(size_t)s0 * 32 + l];
      const float f0l = blo(f0), f0h = bhi(f0);
      float v0l = f0l + fdlo; v0l = v0l > 0.0f ? v0l : LRELU_SLOPE * v0l;
      float v0h = f0h + fdhi; v0h = v0h > 0.0f ? v0h : LRELU_SLOPE * v0h;
      float p0 = fmaf(v0l, awlo, v0h * awhi);
#pragma unroll
      for (int o = 16; o; o >>= 1) p0 += __shfl_xor(p0, o, 64);
      const float e0 = __expf(p0);
      den += e0;
      aclo = fmaf(e0, f0l, aclo); achi = fmaf(e0, f0h, achi);
    }
    const float inv = den > 0.0f ? 1.0f / den : 0.0f;
    if (act) out32[(size_t)n * 32 + l] = packb(aclo * inv, achi * inv);
  }
}

// ---- fused dual-GAT over one CSR pass (shared nbr stream) ----
__global__ void gat12_k(const u16* __restrict__ fsA, const u16* __restrict__ fdA,
                        const float* __restrict__ attnA, u16* __restrict__ outA,
                        const u16* __restrict__ fsB, const u16* __restrict__ fdB,
                        const float* __restrict__ attnB, u16* __restrict__ outB,
                        const int* __restrict__ rowptr, const int* __restrict__ nbr, int N) {
  const int lane = threadIdx.x & 63;
  const int l = lane & 31, half = lane >> 5;
  const int wid = (blockIdx.x * blockDim.x + threadIdx.x) >> 6;
  const int nw = (gridDim.x * blockDim.x) >> 6;
  const float awAlo = attnA[2 * l], awAhi = attnA[2 * l + 1];
  const float awBlo = attnB[2 * l], awBhi = attnB[2 * l + 1];
  const uint32* fsA32 = (const uint32*)fsA;
  const uint32* fdA32 = (const uint32*)fdA;
  const uint32* fsB32 = (const uint32*)fsB;
  const uint32* fdB32 = (const uint32*)fdB;
  uint32* outA32 = (uint32*)outA;
  uint32* outB32 = (uint32*)outB;
  for (int n0 = wid * 2; n0 < N; n0 += nw * 2) {
    const int n = n0 + half;
    const bool act = n < N;
    const int beg = act ? rowptr[n] : 0;
    const int end = act ? rowptr[n + 1] : 0;
    float fdAlo = 0.f, fdAhi = 0.f, fdBlo = 0.f, fdBhi = 0.f;
    if (act) {
      const uint32 fa = fdA32[(size_t)n * 32 + l];
      const uint32 fbv = fdB32[(size_t)n * 32 + l];
      fdAlo = blo(fa); fdAhi = bhi(fa);
      fdBlo = blo(fbv); fdBhi = bhi(fbv);
    }
    float acAlo = 0.f, acAhi = 0.f, denA = 0.f;
    float acBlo = 0.f, acBhi = 0.f, denB = 0.f;
    for (int e = beg; e < end; ++e) {
      const int s0 = nbr[e];
      const uint32 fa = fsA32[(size_t)s0 * 32 + l];
      const uint32 fbv = fsB32[(size_t)s0 * 32 + l];
      const float fal = blo(fa), fah = bhi(fa);
      const float fbl = blo(fbv), fbh = bhi(fbv);
      float vAl = fal + fdAlo; vAl = vAl > 0.f ? vAl : LRELU_SLOPE * vAl;
      float vAh = fah + fdAhi; vAh = vAh > 0.f ? vAh : LRELU_SLOPE * vAh;
      float vBl = fbl + fdBlo; vBl = vBl > 0.f ? vBl : LRELU_SLOPE * vBl;
      float vBh = fbh + fdBhi; vBh = vBh > 0.f ? vBh : LRELU_SLOPE * vBh;
      float pA = fmaf(vAl, awAlo, vAh * awAhi);
      float pB = fmaf(vBl, awBlo, vBh * awBhi);
#pragma unroll
      for (int o = 16; o; o >>= 1) {
        pA += __shfl_xor(pA, o, 64);
        pB += __shfl_xor(pB, o, 64);
      }
      const float eA = __expf(pA), eB = __expf(pB);
      denA += eA; denB += eB;
      acAlo = fmaf(eA, fal, acAlo); acAhi = fmaf(eA, fah, acAhi);
      acBlo = fmaf(eB, fbl, acBlo); acBhi = fmaf(eB, fbh, acBhi);
    }
    if (act) {
      const float iA = denA > 0.f ? 1.0f / denA : 0.f;
      const float iB = denB > 0.f ? 1.0f / denB : 0.f;
      outA32[(size_t)n * 32 + l] = packb(acAlo * iA, acAhi * iA);
      outB32[(size_t)n * 32 + l] = packb(acBlo * iB, acBhi * iB);
    }
  }
}

template <int MODE>
__global__ void cheb32_k(const u16* __restrict__ x, const u16* __restrict__ T0,
                         const u16* __restrict__ Tp, const float* __restrict__ dinv,
                         const float* __restrict__ lam,
                         const int* __restrict__ rowptr, const int* __restrict__ nbr,
                         u16* __restrict__ outT, int N) {
  const float re = 2.0f / lam[0];
  const int lane = threadIdx.x & 63;
  const int l = lane & 31, half = lane >> 5;
  const int wid = (blockIdx.x * blockDim.x + threadIdx.x) >> 6;
  const int nw = (gridDim.x * blockDim.x) >> 6;
  const uint32* x32 = (const uint32*)x;
  const uint32* T032 = (const uint32*)T0;
  const uint32* Tp32 = (const uint32*)Tp;
  uint32* o32 = (uint32*)outT;
  for (int n0 = wid * 2; n0 < N; n0 += nw * 2) {
    const int n = n0 + half;
    const bool act = n < N;
    const int beg = act ? rowptr[n] : 0;
    const int end = act ? rowptr[n + 1] : 0;
    float aclo = 0.0f, achi = 0.0f;
    int e = beg;
    for (; e + 1 < end; e += 2) {
      const int s0 = nbr[e], s1 = nbr[e + 1];
      const uint32 f0 = x32[(size_t)s0 * 32 + l];
      const uint32 f1 = x32[(size_t)s1 * 32 + l];
      const float d0 = dinv[s0], d1 = dinv[s1];
      aclo = fmaf(blo(f0), d0, aclo); achi = fmaf(bhi(f0), d0, achi);
      aclo = fmaf(blo(f1), d1, aclo); achi = fmaf(bhi(f1), d1, achi);
    }
    if (e < end) {
      const int s0 = nbr[e];
      const uint32 f0 = x32[(size_t)s0 * 32 + l];
      const float d0 = dinv[s0];
      aclo = fmaf(blo(f0), d0, aclo); achi = fmaf(bhi(f0), d0, achi);
    }
    if (!act) continue;
    const float dn = dinv[n];
    const float hl = aclo * dn, hh = achi * dn;
    float rl, rh;
    if (MODE == 1) {
      const uint32 t0 = T032[(size_t)n * 32 + l];
      rl = -re * hl + (re - 1.0f) * blo(t0);
      rh = -re * hh + (re - 1.0f) * bhi(t0);
    } else {
      const uint32 t0 = T032[(size_t)n * 32 + l];
      const uint32 tp = Tp32[(size_t)n * 32 + l];
      rl = -2.0f * re * hl + 2.0f * (re - 1.0f) * blo(tp) - blo(t0);
      rh = -2.0f * re * hh + 2.0f * (re - 1.0f) * bhi(tp) - bhi(t0);
    }
    o32[(size_t)n * 32 + l] = packb(rl, rh);
  }
}

__global__ void dinv_k(const int* __restrict__ rowptr, float* __restrict__ dinv, int N) {
  const int i = blockIdx.x * blockDim.x + threadIdx.x;
  if (i < N) {
    const float deg = (float)(rowptr[i + 1] - rowptr[i]);
    dinv[i] = rsqrtf(fmaxf(deg, 1.0f));
  }
}

// ---- mutualistic (bf16 I/O) ----
__global__ void mut_k(const u16* __restrict__ hP, const u16* __restrict__ hS,
                      u16* __restrict__ mP, u16* __restrict__ mS, int N) {
  const int lane = threadIdx.x & 63;
  const int u = (blockIdx.x * blockDim.x + threadIdx.x) >> 6;
  if (u >= N) return;
  const float p = b2f(hP[(size_t)u * 64 + lane]);
  const float s = b2f(hS[(size_t)u * 64 + lane]);
  const float m = p * s;
  float mxp = p, mxs = s;
#pragma unroll
  for (int o = 32; o; o >>= 1) {
    mxp = fmaxf(mxp, __shfl_xor(mxp, o, 64));
    mxs = fmaxf(mxs, __shfl_xor(mxs, o, 64));
  }
  const float ep = __expf(p - mxp);
  const float es = __expf(s - mxs);
  float sp = ep, ss = es;
#pragma unroll
  for (int o = 32; o; o >>= 1) {
    sp += __shfl_xor(sp, o, 64);
    ss += __shfl_xor(ss, o, 64);
  }
  mP[(size_t)u * 64 + lane] = f2b(m * (ep / sp));
  mS[(size_t)u * 64 + lane] = f2b(m * (es / ss));
}

// ---- edge dot body (4 edges/iter: 2 halves x ILP-2) ----
__device__ __forceinline__ void dot_body(const uint32* A32, const uint32* B32,
                                         const int* src, const int* dst,
                                         float* out, int E,
                                         int wid, int nw, int l, int half) {
  for (int e0 = wid * 4; e0 < E; e0 += nw * 4) {
    const int eA = e0 + half;
    const int eB = e0 + 2 + half;
    const int eAc = eA < E ? eA : E - 1;
    const int eBc = eB < E ? eB : E - 1;
    const int sA = src[eAc], dA = dst[eAc];
    const int sB = src[eBc], dB = dst[eBc];
    const uint32 a0 = A32[(size_t)sA * 32 + l];
    const uint32 b0 = B32[(size_t)dA * 32 + l];
    const uint32 a1 = A32[(size_t)sB * 32 + l];
    const uint32 b1 = B32[(size_t)dB * 32 + l];
    float p0 = fmaf(blo(a0), blo(b0), bhi(a0) * bhi(b0));
    float p1 = fmaf(blo(a1), blo(b1), bhi(a1) * bhi(b1));
#pragma unroll
    for (int o = 16; o; o >>= 1) {
      p0 += __shfl_xor(p0, o, 64);
      p1 += __shfl_xor(p1, o, 64);
    }
    if (l == 0) {
      if (eA < E) out[eA] = p0;
      if (eB < E) out[eB] = p1;
    }
  }
}

// ---- paired dots: two lists over same tables, BLOCK-split grid ----
__global__ void dot_pair_k(const u16* __restrict__ A, const u16* __restrict__ Bm,
                           const int* __restrict__ src1, const int* __restrict__ dst1,
                           float* __restrict__ out1, int E1,
                           const int* __restrict__ src2, const int* __restrict__ dst2,
                           float* __restrict__ out2, int E2) {
  const int lane = threadIdx.x & 63;
  const int l = lane & 31, half = lane >> 5;
  const int halfg = gridDim.x >> 1;
  const bool job1 = (int)blockIdx.x < halfg;
  const int bid = job1 ? blockIdx.x : blockIdx.x - halfg;
  const int wid = (bid * blockDim.x + threadIdx.x) >> 6;
  const int nw = (halfg * blockDim.x) >> 6;
  const uint32* A32 = (const uint32*)A;
  const uint32* B32 = (const uint32*)Bm;
  if (job1) dot_body(A32, B32, src1, dst1, out1, E1, wid, nw, l, half);
  else      dot_body(A32, B32, src2, dst2, out2, E2, wid, nw, l, half);
}

// ---------------------------------------------------------------------------

static void build_csr(const int* key, const int* other, int E, int N,
                      int* rowptr, int* srt, int* cursor, int* bsum,
                      hipStream_t stream) {
  const int n1 = N + 1;
  hipMemsetAsync(cursor, 0, (size_t)n1 * 4, stream);
  hist_k<<<(E + 255) / 256, 256, 0, stream>>>(key, cursor, E);
  const int nb = (n1 + 1023) / 1024;
  scan1_k<<<nb, 256, 0, stream>>>(cursor, rowptr, bsum, n1);
  scan2_k<<<1, 64, 0, stream>>>(bsum, nb);
  scan3_k<<<(n1 + 255) / 256, 256, 0, stream>>>(rowptr, bsum, n1);
  hipMemcpyAsync(cursor, rowptr, (size_t)N * 4, hipMemcpyDeviceToDevice, stream);
  scatter_k<<<(E + 255) / 256, 256, 0, stream>>>(key, other, cursor, srt, E);
}

extern "C" void kernel_launch(void* const* d_in, const int* in_sizes, int n_in,
                              void* d_out, int out_size, void* d_ws, size_t ws_size,
                              hipStream_t stream) {
  const float* user_emb = (const float*)d_in[0];
  const float* item_emb = (const float*)d_in[1];
  const int* rate_src = (const int*)d_in[2];
  const int* rate_dst = (const int*)d_in[3];
  const int* link_src = (const int*)d_in[4];
  const int* link_dst = (const int*)d_in[5];
  const int* neg_rate_src = (const int*)d_in[6];
  const int* neg_rate_dst = (const int*)d_in[7];
  const int* neg_link_src = (const int*)d_in[8];
  const int* neg_link_dst = (const int*)d_in[9];
  const float* lam = (const float*)d_in[10];
  const float* gat_Wsrc = (const float*)d_in[11];
  const float* gat_bsrc = (const float*)d_in[12];
  const float* gat_Wdst = (const float*)d_in[13];
  const float* gat_bdst = (const float*)d_in[14];
  const float* gat_attn = (const float*)d_in[15];
  const float* W_out = (const float*)d_in[16];
  const float* b_out = (const float*)d_in[17];
  const float* cheb_W = (const float*)d_in[18];
  const float* cheb_b = (const float*)d_in[19];
  const float* Wc = (const float*)d_in[20];
  const float* bc = (const float*)d_in[21];
  const float* Wsm = (const float*)d_in[22];
  const float* bs = (const float*)d_in[23];
  const float* WpP = (const float*)d_in[24];
  const float* bpP = (const float*)d_in[25];
  const float* WpS = (const float*)d_in[26];
  const float* bpS = (const float*)d_in[27];

  const int NU = in_sizes[0] / 64;
  const int NI = in_sizes[1] / 64;
  const int NR = in_sizes[2];
  const int NL = in_sizes[4];
  const int NMAX = NU > NI ? NU : NI;
  const size_t MAT = (size_t)NMAX * 64;
  const int FR = 4096;

  u16* ub = (u16*)d_ws;
  u16* ib = ub + (size_t)NU * 64;
  u16* B0 = ib + (size_t)NI * 64;
  u16* B1 = B0 + MAT;
  u16* B2 = B1 + MAT;
  u16* B3 = B2 + MAT;
  u16* B4 = B3 + MAT;
  u16* B5 = B4 + MAT;
  u16* B6 = B5 + MAT;
  u16* B7 = B6 + MAT;
  u16* fb = B7 + MAT;
  u16* fbWsrc = fb;
  u16* fbWdst = fb + 5 * FR;
  u16* fbWout = fb + 10 * FR;
  u16* fbCheb = fb + 12 * FR;
  u16* fbWc = fb + 15 * FR;
  u16* fbWsm = fb + 17 * FR;
  u16* fbWpP = fb + 19 * FR;
  u16* fbWpS = fb + 21 * FR;
  int* ip = (int*)(fb + 23 * FR);
  int* rp_rd = ip;
  int* rp_rs = rp_rd + (NI + 1);
  int* rp_ld = rp_rs + (NU + 1);
  int* srt_rd = rp_ld + (NU + 1);
  int* srt_rs = srt_rd + NR;
  int* srt_ld = srt_rs + NR;
  int* cursor = srt_ld + NL;
  int* bsum = cursor + (NMAX + 1);
  float* dinv = (float*)(bsum + 256);

  const int B64 = 64;

  // ---- bf16 copies + W fragment prep (2 launches total) ----
  cvt2_k<<<2048, 256, 0, stream>>>((const float4*)user_emb, (ushort4*)ub, NU * 16,
                                   (const float4*)item_emb, (ushort4*)ib, NI * 16);
  wfrag_all_k<<<368, 256, 0, stream>>>(gat_Wsrc, gat_Wdst, W_out, cheb_W,
                                       Wc, Wsm, WpP, WpS, fb);

  // ---- 3 CSR groupings ----
  build_csr(rate_dst, rate_src, NR, NI, rp_rd, srt_rd, cursor, bsum, stream);
  build_csr(rate_src, rate_dst, NR, NU, rp_rs, srt_rs, cursor, bsum, stream);
  build_csr(link_dst, link_src, NL, NU, rp_ld, srt_ld, cursor, bsum, stream);

  // ---- projections (2-output MFMA): fs0->B0, fd1->B1 ; fd2->B2, fd3->B3 ----
  mfma_g2_k<<<MFMA_BLOCKS, 256, 0, stream>>>(ub, fbWsrc + 0 * FR, fbWdst + 1 * FR,
      gat_bsrc + 0 * B64, gat_bdst + 1 * B64, B0, B1, NU);
  mfma_g2_k<<<MFMA_BLOCKS, 256, 0, stream>>>(ub, fbWdst + 2 * FR, fbWdst + 3 * FR,
      gat_bdst + 2 * B64, gat_bdst + 3 * B64, B2, B3, NU);
  // ---- item projections: fd0->B4, fs1->B5 ----
  mfma_g2_k<<<MFMA_BLOCKS, 256, 0, stream>>>(ib, fbWdst + 0 * FR, fbWsrc + 1 * FR,
      gat_bdst + 0 * B64, gat_bsrc + 1 * B64, B4, B5, NI);

  // ---- gat0 -> B6 (h1_item) ----
  gat32_k<<<EDGE_BLOCKS, 256, 0, stream>>>(B0, B4, gat_attn + 0 * B64, rp_rd, srt_rd, B6, NI);

  // ---- fs2 = h1_item @ Ws2 -> B0 ----
  mfma_g_k<1><<<MFMA_BLOCKS, 256, 0, stream>>>(B6, nullptr, nullptr,
      fbWsrc + 2 * FR, nullptr, nullptr, gat_bsrc + 2 * B64, B0, NI);

  // ---- fused gat1+gat2 over rate-by-user: B7 (h2_user), B4 (item_infl) ----
  gat12_k<<<EDGE_BLOCKS, 256, 0, stream>>>(B5, B1, gat_attn + 1 * B64, B7,
                                           B0, B2, gat_attn + 2 * B64, B4,
                                           rp_rs, srt_rs, NU);

  // ---- fs3 = h2_user @ Ws3 -> B5 ; gat3 -> B2 (social_item) ----
  mfma_g_k<1><<<MFMA_BLOCKS, 256, 0, stream>>>(B7, nullptr, nullptr,
      fbWsrc + 3 * FR, nullptr, nullptr, gat_bsrc + 3 * B64, B5, NU);
  gat32_k<<<EDGE_BLOCKS, 256, 0, stream>>>(B5, B3, gat_attn + 3 * B64, rp_ld, srt_ld, B2, NU);

  // ---- user_pref = [item_infl(B4), social_item(B2)] @ W_out -> B0 ----
  mfma_g_k<2><<<MFMA_BLOCKS, 256, 0, stream>>>(B4, B2, nullptr,
      fbWout + 0 * FR, fbWout + 1 * FR, nullptr, b_out, B0, NU);

  // ---- ChebConv(k=3): T1->B5, T2->B3, rst->B6 ----
  dinv_k<<<(NU + 255) / 256, 256, 0, stream>>>(rp_ld, dinv, NU);
  cheb32_k<1><<<EDGE_BLOCKS, 256, 0, stream>>>(ub, ub, nullptr, dinv, lam,
                                               rp_ld, srt_ld, B5, NU);
  cheb32_k<2><<<EDGE_BLOCKS, 256, 0, stream>>>(B5, ub, B5, dinv, lam,
                                               rp_ld, srt_ld, B3, NU);
  mfma_g_k<3><<<MFMA_BLOCKS, 256, 0, stream>>>(ub, B5, B3,
      fbCheb + 0 * FR, fbCheb + 1 * FR, fbCheb + 2 * FR, cheb_b, B6, NU);

  // ---- rst projections: fs4->B4, fd4->B2 ; gat4 -> B5 (user_social) ----
  mfma_g2_k<<<MFMA_BLOCKS, 256, 0, stream>>>(B6, fbWsrc + 4 * FR, fbWdst + 4 * FR,
      gat_bsrc + 4 * B64, gat_bdst + 4 * B64, B4, B2, NU);
  gat32_k<<<EDGE_BLOCKS, 256, 0, stream>>>(B4, B2, gat_attn + 4 * B64, rp_ld, srt_ld, B5, NU);

  // ---- mutualistic: h_uP->B4 (job A), h_uS->B2 (job B) ----
  mfma_pair_k<<<2 * MFMA_BLOCKS, 256, 0, stream>>>(
      B0, ub, fbWc + 0 * FR, fbWc + 1 * FR, bc, B4, NU,
      B5, ub, fbWsm + 0 * FR, fbWsm + 1 * FR, bs, B2, NU);
  mut_k<<<(NU + 3) / 4, 256, 0, stream>>>(B4, B2, B3, B7, NU);  // mP->B3, mS->B7
  // h_new_P->B0 (job A), h_new_S->B5 (job B)
  mfma_pair_k<<<2 * MFMA_BLOCKS, 256, 0, stream>>>(
      B3, B4, fbWpP + 0 * FR, fbWpP + 1 * FR, bpP, B0, NU,
      B7, B2, fbWpS + 0 * FR, fbWpS + 1 * FR, bpS, B5, NU);

  // ---- predictors (block-split pairs) ----
  float* out = (float*)d_out;
  dot_pair_k<<<EDGE_BLOCKS, 256, 0, stream>>>(B0, ib, rate_src, rate_dst, out, NR,
                                              neg_rate_src, neg_rate_dst, out + NR, NR);
  dot_pair_k<<<EDGE_BLOCKS, 256, 0, stream>>>(B5, ub, link_src, link_dst,
                                              out + 2 * (size_t)NR, NL,
                                              neg_link_src, neg_link_dst,
                                              out + 2 * (size_t)NR + NL, NL);
}